// Round 15
// baseline (181.128 us; speedup 1.0000x reference)
//
#include <hip/hip_runtime.h>
#include <math.h>

#define DM 512
#define NH 8
#define DH 64
#define SEQ 512
#define BATCH 8
#define MR 1023
#define PE_OFF 4489

typedef float4 f4;
typedef __attribute__((ext_vector_type(8))) short bf16x8;
typedef __attribute__((ext_vector_type(4))) float f32x4;
typedef __attribute__((ext_vector_type(8))) unsigned short u16x8;
typedef __attribute__((ext_vector_type(4))) unsigned short u16x4;

__device__ __forceinline__ unsigned short f2bf(float f) {
    unsigned x = __float_as_uint(f);
    unsigned r = x + 0x7fffu + ((x >> 16) & 1u);
    return (unsigned short)(r >> 16);
}
__device__ __forceinline__ float bf2f(unsigned short h) {
    return __uint_as_float(((unsigned)h) << 16);
}
__device__ __forceinline__ f32x4 mfma16(bf16x8 a, bf16x8 b, f32x4 c) {
    return __builtin_amdgcn_mfma_f32_16x16x32_bf16(a, b, c, 0, 0, 0);
}
// async global->LDS, 16B per lane, dest = uniform base + lane*16
__device__ __forceinline__ void gll16(const unsigned short* g, unsigned short* l) {
    __builtin_amdgcn_global_load_lds(
        (const __attribute__((address_space(1))) unsigned int*)g,
        (__attribute__((address_space(3))) unsigned int*)l, 16, 0, 0);
}

// ---------------------------------------------------------------------------
// fp32 -> (bf16 hi, bf16 lo), stored PRE-SWIZZLED for gll staging:
// col' = col ^ (((row>>1)&3)<<3)
// ---------------------------------------------------------------------------
__device__ __forceinline__ void cvt8s(const float* __restrict__ src,
                                      unsigned short* __restrict__ hi,
                                      unsigned short* __restrict__ lo, int i) {
    const int row = i >> 9, col = i & 511;
    const int j = (i & ~511) | (col ^ (((row >> 1) & 3) << 3));
    f4 a = *(const f4*)&src[i];
    f4 b = *(const f4*)&src[i + 4];
    float v[8] = {a.x, a.y, a.z, a.w, b.x, b.y, b.z, b.w};
    u16x8 h, l;
#pragma unroll
    for (int e = 0; e < 8; ++e) {
        unsigned short hb = f2bf(v[e]);
        h[e] = hb;
        l[e] = f2bf(v[e] - bf2f(hb));
    }
    *(u16x8*)&hi[j] = h;
    *(u16x8*)&lo[j] = l;
}

__global__ __launch_bounds__(256) void cvt_all_kernel(
    const float* __restrict__ x,
    const float* __restrict__ w0, const float* __restrict__ w1,
    const float* __restrict__ w2, const float* __restrict__ w3,
    const float* __restrict__ w4, const float* __restrict__ pe,
    unsigned short* __restrict__ xh, unsigned short* __restrict__ xl,
    unsigned short* __restrict__ wb,
    unsigned short* __restrict__ peh, unsigned short* __restrict__ pel)
{
    const int bid = blockIdx.x, tid = threadIdx.x;
    if (bid < 1024) {
        cvt8s(x, xh, xl, (bid * 256 + tid) * 8);
    } else if (bid < 1664) {
        const int wsel = (bid - 1024) >> 7;
        const float* src = (wsel == 0) ? w0 : (wsel == 1) ? w1 :
                           (wsel == 2) ? w2 : (wsel == 3) ? w3 : w4;
        unsigned short* hi = wb + (size_t)wsel * 524288;
        cvt8s(src, hi, hi + 262144, (((bid - 1024) & 127) * 256 + tid) * 8);
    } else {
        const int i = ((bid - 1664) * 256 + tid) * 8;
        if (i < 523776) cvt8s(pe, peh, pel, i);
    }
}

// ---------------------------------------------------------------------------
// Split-bf16 GEMM core, 128x64 tile, global_load_lds staging (R14, proven).
// ---------------------------------------------------------------------------
__device__ __forceinline__ void gemm_core128(
    const unsigned short* __restrict__ Ah, const unsigned short* __restrict__ Al,
    const unsigned short* __restrict__ Wh, const unsigned short* __restrict__ Wl,
    int m0, int n0, f32x4 acc[4][2],
    unsigned short* LAh, unsigned short* LAl,
    unsigned short* LBh, unsigned short* LBl)
{
    const int tid = threadIdx.x;
    const int lane = tid & 63, wid = tid >> 6;
    const int wm = (wid >> 1) << 6, wn = (wid & 1) << 5;
    const int fr = lane & 15, g = lane >> 4;
    const int crow = lane >> 2;
    const int ccol = (lane & 3) << 3;

#pragma unroll
    for (int i = 0; i < 4; ++i)
#pragma unroll
        for (int j = 0; j < 2; ++j)
            acc[i][j] = (f32x4){0.f, 0.f, 0.f, 0.f};

    const size_t ga1 = (size_t)(m0 + (wid << 4) + crow) * DM + ccol;
    const size_t ga2 = ga1 + (size_t)64 * DM;
    const size_t gb  = (size_t)(n0 + (wid << 4) + crow) * DM + ccol;
    const int lbase = wid << 9;
    const int cswz = (g ^ ((fr >> 1) & 3)) << 3;

    for (int k0 = 0; k0 < DM; k0 += 32) {
        if (k0) __syncthreads();
        gll16(Ah + ga1 + k0, LAh + lbase);
        gll16(Ah + ga2 + k0, LAh + lbase + 2048);
        gll16(Al + ga1 + k0, LAl + lbase);
        gll16(Al + ga2 + k0, LAl + lbase + 2048);
        gll16(Wh + gb + k0, LBh + lbase);
        gll16(Wl + gb + k0, LBl + lbase);
        __syncthreads();

        bf16x8 a_h[4], a_l[4], b_h[2], b_l[2];
#pragma unroll
        for (int mi = 0; mi < 4; ++mi) {
            const int ro = (wm + (mi << 4) + fr) << 5;
            a_h[mi] = *(const bf16x8*)&LAh[ro + cswz];
            a_l[mi] = *(const bf16x8*)&LAl[ro + cswz];
        }
#pragma unroll
        for (int ni = 0; ni < 2; ++ni) {
            const int ro = (wn + (ni << 4) + fr) << 5;
            b_h[ni] = *(const bf16x8*)&LBh[ro + cswz];
            b_l[ni] = *(const bf16x8*)&LBl[ro + cswz];
        }
#pragma unroll
        for (int mi = 0; mi < 4; ++mi)
#pragma unroll
            for (int ni = 0; ni < 2; ++ni) {
                acc[mi][ni] = mfma16(a_h[mi], b_h[ni], acc[mi][ni]);
                acc[mi][ni] = mfma16(a_h[mi], b_l[ni], acc[mi][ni]);
                acc[mi][ni] = mfma16(a_l[mi], b_h[ni], acc[mi][ni]);
            }
    }
}

#define GEMM_LDS \
    __shared__ unsigned short LAh[128 * 32], LAl[128 * 32]; \
    __shared__ unsigned short LBh[64 * 32], LBl[64 * 32];

// ---------------------------------------------------------------------------
// Fused QKV projection + Rm/rcorr. Flat grid 832 (rm blocks first).
// ---------------------------------------------------------------------------
__global__ __launch_bounds__(256) void qkv_rm_kernel(
    const unsigned short* __restrict__ xh, const unsigned short* __restrict__ xl,
    const unsigned short* __restrict__ wb,
    const unsigned short* __restrict__ peh, const unsigned short* __restrict__ pel,
    const float* __restrict__ bq, const float* __restrict__ bk,
    const float* __restrict__ bv, const float* __restrict__ u,
    const float* __restrict__ vb,
    unsigned short* __restrict__ qh, unsigned short* __restrict__ ql,
    unsigned short* __restrict__ kh, unsigned short* __restrict__ kl,
    unsigned short* __restrict__ vth, unsigned short* __restrict__ vtl,
    unsigned short* __restrict__ rmh, unsigned short* __restrict__ rml,
    float* __restrict__ rc)
{
    GEMM_LDS
    const int bid = blockIdx.x;
    const int tid = threadIdx.x, lane = tid & 63, wid = tid >> 6;
    const int wm = (wid >> 1) << 6, wn = (wid & 1) << 5;
    const int fr = lane & 15, g = lane >> 4;

    if (bid < 64) {
        const int n0 = (bid & 7) << 6, m0 = (bid >> 3) << 7;
        const unsigned short* wrh = wb + 4 * 524288;
        const unsigned short* wrl = wrh + 262144;
        f32x4 acc[4][2];
        gemm_core128(peh, pel, wrh, wrl, m0, n0, acc, LAh, LAl, LBh, LBl);

        const int h = n0 >> 6;
        float part[4][4];
        float wgt[2];
#pragma unroll
        for (int ni = 0; ni < 2; ++ni) {
            const int d = wn + (ni << 4) + fr;
            wgt[ni] = vb[(h << 6) + d] - u[(h << 6) + d];
        }
#pragma unroll
        for (int mi = 0; mi < 4; ++mi)
#pragma unroll
            for (int r = 0; r < 4; ++r) part[mi][r] = 0.f;

#pragma unroll
        for (int ni = 0; ni < 2; ++ni) {
            const int n_g = n0 + wn + (ni << 4) + fr;
            const int d = n_g & 63;
#pragma unroll
            for (int mi = 0; mi < 4; ++mi)
#pragma unroll
                for (int r = 0; r < 4; ++r) {
                    const int dd = m0 + wm + (mi << 4) + (g << 2) + r;
                    const float val = acc[mi][ni][r];
                    const size_t o = (((size_t)h << 10) + dd) * DH + d;
                    const unsigned short hb = f2bf(val);
                    rmh[o] = hb;
                    rml[o] = f2bf(val - bf2f(hb));
                    part[mi][r] = fmaf(wgt[ni], val, part[mi][r]);
                }
        }

        __syncthreads();
        float* cbuf = (float*)LAh;
#pragma unroll
        for (int mi = 0; mi < 4; ++mi)
#pragma unroll
            for (int r = 0; r < 4; ++r) {
                float v = part[mi][r];
#pragma unroll
                for (int off = 8; off; off >>= 1) v += __shfl_xor(v, off, 16);
                if (fr == 0)
                    cbuf[((wid & 1) << 7) + wm + (mi << 4) + (g << 2) + r] = v;
            }
        __syncthreads();
        if (tid < 128)
            rc[((size_t)h << 10) + m0 + tid] = cbuf[tid] + cbuf[128 + tid];
        return;
    }

    const int t = bid - 64;
    const int wsel = t >> 8;
    const int rest = t & 255;
    const int n0 = (rest & 7) << 6, m0 = (rest >> 3) << 7;
    const unsigned short* Wh = wb + (size_t)wsel * 524288;
    const unsigned short* Wl = Wh + 262144;
    f32x4 acc[4][2];
    gemm_core128(xh, xl, Wh, Wl, m0, n0, acc, LAh, LAl, LBh, LBl);

    const float* bias = (wsel == 0) ? bq : (wsel == 1) ? bk : bv;

    if (wsel < 2) {
        unsigned short* oh = (wsel == 0) ? qh : kh;
        unsigned short* ol = (wsel == 0) ? ql : kl;
#pragma unroll
        for (int ni = 0; ni < 2; ++ni) {
            const int n_g = n0 + wn + (ni << 4) + fr;
            float bvv = bias[n_g] + ((wsel == 0) ? u[n_g] : 0.f);
            const int h = n_g >> 6, d = n_g & 63;
#pragma unroll
            for (int mi = 0; mi < 4; ++mi)
#pragma unroll
                for (int r = 0; r < 4; ++r) {
                    const int m_g = m0 + wm + (mi << 4) + (g << 2) + r;
                    const int b = m_g >> 9, s = m_g & 511;
                    const float val = acc[mi][ni][r] + bvv;
                    const size_t o = ((size_t)(b * NH + h) * SEQ + s) * DH + d;
                    const unsigned short hb = f2bf(val);
                    oh[o] = hb;
                    ol[o] = f2bf(val - bf2f(hb));
                }
        }
    } else {
#pragma unroll
        for (int ni = 0; ni < 2; ++ni) {
            const int n_g = n0 + wn + (ni << 4) + fr;
            const float bvv = bias[n_g];
            const int h = n_g >> 6, d = n_g & 63;
#pragma unroll
            for (int mi = 0; mi < 4; ++mi) {
                const int m_b = m0 + wm + (mi << 4) + (g << 2);
                const int b = m_b >> 9, s = m_b & 511;
                u16x4 hv, lv;
#pragma unroll
                for (int r = 0; r < 4; ++r) {
                    const float val = acc[mi][ni][r] + bvv;
                    hv[r] = f2bf(val);
                    lv[r] = f2bf(val - bf2f(hv[r]));
                }
                const size_t o = ((size_t)(b * NH + h) * DH + d) * SEQ + s;
                *(u16x4*)&vth[o] = hv;
                *(u16x4*)&vtl[o] = lv;
            }
        }
    }
}

// out = ctx @ wo^T + bo  (f32 out). grid (8, 32).
__global__ __launch_bounds__(256) void out_kernel(
    const unsigned short* __restrict__ cth, const unsigned short* __restrict__ ctl,
    const unsigned short* __restrict__ woh, const unsigned short* __restrict__ wol,
    const float* __restrict__ bo, float* __restrict__ out)
{
    GEMM_LDS
    const int n0 = blockIdx.x << 6, m0 = blockIdx.y << 7;
    f32x4 acc[4][2];
    gemm_core128(cth, ctl, woh, wol, m0, n0, acc, LAh, LAl, LBh, LBl);

    const int tid = threadIdx.x, lane = tid & 63, wid = tid >> 6;
    const int wm = (wid >> 1) << 6, wn = (wid & 1) << 5;
    const int fr = lane & 15, g = lane >> 4;
#pragma unroll
    for (int ni = 0; ni < 2; ++ni) {
        const int n_g = n0 + wn + (ni << 4) + fr;
        const float bvv = bo[n_g];
#pragma unroll
        for (int mi = 0; mi < 4; ++mi)
#pragma unroll
            for (int r = 0; r < 4; ++r) {
                const int m_g = m0 + wm + (mi << 4) + (g << 2) + r;
                out[(size_t)m_g * DM + n_g] = acc[mi][ni][r] + bvv;
            }
    }
}

// ---------------------------------------------------------------------------
// MFMA flash attention, j-split, NO launch_bounds cap (R6-R8's phantom-write
// regressions traced to scratch spill from capped unified VGPR+AGPR budget).
// Block = (i-tile 8, j-half 2, bhid 64) = 1024 blocks, 4 waves x 16 rows,
// 4 j-tiles of 64 per block. K LDS-staged + T14 prefetch; V direct global
// (L2-resident); LDS 46.6 KB -> 3 blocks/CU. f32 partials + merge kernel.
// ---------------------------------------------------------------------------
__global__ __launch_bounds__(256) void attn_kernel(
    const unsigned short* __restrict__ qh_g, const unsigned short* __restrict__ ql_g,
    const unsigned short* __restrict__ kh_g, const unsigned short* __restrict__ kl_g,
    const unsigned short* __restrict__ vh_g, const unsigned short* __restrict__ vl_g,
    const unsigned short* __restrict__ rmh, const unsigned short* __restrict__ rml,
    const float* __restrict__ rc,
    float* __restrict__ Op, float* __restrict__ Mp, float* __restrict__ Lp)
{
    __shared__ unsigned short Kh[64][72], Kl[64][72];
    __shared__ unsigned short Pdd[4][16][84];
    __shared__ float Pt[4][16][68];

    const int tid = threadIdx.x;
    const int lane = tid & 63, wid = tid >> 6;
    const int g = lane >> 4, c = lane & 15;
    const int i0 = blockIdx.x << 6;
    const int jh = blockIdx.y;
    const int bhid = blockIdx.z;
    const int h = bhid & 7;
    const int R0 = i0 + (wid << 4);
    const size_t bh = (size_t)bhid * (SEQ * DH);
    const int jbase = jh << 8;

    const int srow = tid >> 3;
    const int sch = (tid & 7) << 3;

    bf16x8 qhf[2], qlf[2];
#pragma unroll
    for (int ks = 0; ks < 2; ++ks) {
        const size_t qo = bh + (size_t)(R0 + c) * DH + (ks << 5) + (g << 3);
        qhf[ks] = *(const bf16x8*)&qh_g[qo];
        qlf[ks] = *(const bf16x8*)&ql_g[qo];
    }

    f32x4 Oacc[4];
#pragma unroll
    for (int nf = 0; nf < 4; ++nf) Oacc[nf] = (f32x4){0.f, 0.f, 0.f, 0.f};
    float m_r[4] = {-3e38f, -3e38f, -3e38f, -3e38f};
    float l_r[4] = {0.f, 0.f, 0.f, 0.f};

    const float* rch = rc + (h << 10);
    const unsigned short* rmhh = rmh + ((size_t)h << 16);
    const unsigned short* rmlh = rml + ((size_t)h << 16);

    // T14 prefetch registers (K only)
    u16x8 p0, p1, p2, p3;
    {
        const size_t kb = bh + (size_t)(jbase + srow) * DH + sch;
        p0 = *(const u16x8*)&kh_g[kb];
        p1 = *(const u16x8*)&kh_g[kb + 32 * DH];
        p2 = *(const u16x8*)&kl_g[kb];
        p3 = *(const u16x8*)&kl_g[kb + 32 * DH];
    }

#pragma unroll
    for (int t = 0; t < 4; ++t) {
        const int j0 = jbase + (t << 6);
        __syncthreads();
        *(u16x8*)&Kh[srow][sch] = p0;
        *(u16x8*)&Kh[srow + 32][sch] = p1;
        *(u16x8*)&Kl[srow][sch] = p2;
        *(u16x8*)&Kl[srow + 32][sch] = p3;
        __syncthreads();
        if (t < 3) {
            const size_t kb = bh + (size_t)(j0 + 64 + srow) * DH + sch;
            p0 = *(const u16x8*)&kh_g[kb];
            p1 = *(const u16x8*)&kh_g[kb + 32 * DH];
            p2 = *(const u16x8*)&kl_g[kb];
            p3 = *(const u16x8*)&kl_g[kb + 32 * DH];
        }

        __builtin_amdgcn_s_setprio(1);
        f32x4 accs[4];
#pragma unroll
        for (int nf = 0; nf < 4; ++nf) accs[nf] = (f32x4){0.f, 0.f, 0.f, 0.f};
#pragma unroll
        for (int ks = 0; ks < 2; ++ks)
#pragma unroll
            for (int nf = 0; nf < 4; ++nf) {
                bf16x8 b_h = *(const bf16x8*)&Kh[(nf << 4) + c][(ks << 5) + (g << 3)];
                bf16x8 b_l = *(const bf16x8*)&Kl[(nf << 4) + c][(ks << 5) + (g << 3)];
                accs[nf] = mfma16(qhf[ks], b_h, accs[nf]);
                accs[nf] = mfma16(qhf[ks], b_l, accs[nf]);
                accs[nf] = mfma16(qlf[ks], b_h, accs[nf]);
            }

        const int base_g = j0 - R0 + 496;
#pragma unroll
        for (int f = 0; f < 5; ++f) {
            f32x4 ap = (f32x4){0.f, 0.f, 0.f, 0.f};
#pragma unroll
            for (int ks = 0; ks < 2; ++ks) {
                const size_t ro = (size_t)(base_g + (f << 4) + c) * DH
                                + (ks << 5) + (g << 3);
                bf16x8 b_h = *(const bf16x8*)&rmhh[ro];
                bf16x8 b_l = *(const bf16x8*)&rmlh[ro];
                ap = mfma16(qhf[ks], b_h, ap);
                ap = mfma16(qhf[ks], b_l, ap);
                ap = mfma16(qlf[ks], b_h, ap);
            }
            const float rcv = rch[base_g + (f << 4) + c];
#pragma unroll
            for (int r = 0; r < 4; ++r)
                Pdd[wid][(g << 2) + r][(f << 4) + c] = f2bf(ap[r] + rcv);
        }
        __builtin_amdgcn_s_setprio(0);

#pragma unroll
        for (int r = 0; r < 4; ++r) {
            const int irow = (g << 2) + r;
            float sc[4];
#pragma unroll
            for (int nf = 0; nf < 4; ++nf) {
                const int ddl = (nf << 4) + c - irow + 15;
                sc[nf] = (accs[nf][r] + bf2f(Pdd[wid][irow][ddl])) * 0.125f;
            }
            float mt = fmaxf(fmaxf(sc[0], sc[1]), fmaxf(sc[2], sc[3]));
#pragma unroll
            for (int off = 8; off; off >>= 1) mt = fmaxf(mt, __shfl_xor(mt, off, 16));
            const float mn = fmaxf(m_r[r], mt);
            const float alpha = __expf(m_r[r] - mn);
            m_r[r] = mn;
            float rs = 0.f;
#pragma unroll
            for (int nf = 0; nf < 4; ++nf) {
                const float p = __expf(sc[nf] - mn);
                Pt[wid][irow][(nf << 4) + c] = p;
                rs += p;
            }
#pragma unroll
            for (int off = 8; off; off >>= 1) rs += __shfl_xor(rs, off, 16);
            l_r[r] = l_r[r] * alpha + rs;
#pragma unroll
            for (int nf = 0; nf < 4; ++nf) Oacc[nf][r] *= alpha;
        }

        // PV: A = P (hi/lo from Pt), B = Vt direct global (L2-resident)
        __builtin_amdgcn_s_setprio(1);
#pragma unroll
        for (int ks = 0; ks < 2; ++ks) {
            f4 pv0 = *(const f4*)&Pt[wid][c][(ks << 5) + (g << 3)];
            f4 pv1 = *(const f4*)&Pt[wid][c][(ks << 5) + (g << 3) + 4];
            float pv[8] = {pv0.x, pv0.y, pv0.z, pv0.w, pv1.x, pv1.y, pv1.z, pv1.w};
            bf16x8 ph, pl;
#pragma unroll
            for (int e = 0; e < 8; ++e) {
                const unsigned short hb = f2bf(pv[e]);
                ph[e] = (short)hb;
                pl[e] = (short)f2bf(pv[e] - bf2f(hb));
            }
#pragma unroll
            for (int nf = 0; nf < 4; ++nf) {
                const size_t vo = bh + (size_t)((nf << 4) + c) * SEQ + j0
                                + (ks << 5) + (g << 3);
                bf16x8 v_h = *(const bf16x8*)&vh_g[vo];
                bf16x8 v_l = *(const bf16x8*)&vl_g[vo];
                Oacc[nf] = mfma16(ph, v_h, Oacc[nf]);
                Oacc[nf] = mfma16(ph, v_l, Oacc[nf]);
                Oacc[nf] = mfma16(pl, v_h, Oacc[nf]);
            }
        }
        __builtin_amdgcn_s_setprio(0);
    }

    // epilogue: f32 partials per j-half
    const size_t prow = (size_t)jh * 32768 + (size_t)bhid * 512;
#pragma unroll
    for (int nf = 0; nf < 4; ++nf)
#pragma unroll
        for (int r = 0; r < 4; ++r) {
            const int s = R0 + (g << 2) + r;
            Op[(prow + s) * 64 + (nf << 4) + c] = Oacc[nf][r];
        }
    if (c == 0) {
#pragma unroll
        for (int r = 0; r < 4; ++r) {
            const int s = R0 + (g << 2) + r;
            Mp[prow + s] = m_r[r];
            Lp[prow + s] = l_r[r];
        }
    }
}

// 2-way flash combine -> ctx bf16 hi/lo, pre-swizzled for out_kernel's gll
__global__ __launch_bounds__(256) void merge_kernel(
    const float* __restrict__ Op, const float* __restrict__ Mp,
    const float* __restrict__ Lp,
    unsigned short* __restrict__ cth, unsigned short* __restrict__ ctl)
{
    const int idx = blockIdx.x * 256 + threadIdx.x;   // B*H*S*16
    const int d4 = (idx & 15) << 2;
    const int rowid = idx >> 4;                        // bhid*512 + s
    const int bhid = rowid >> 9, s = rowid & 511;
    const int b = bhid >> 3, h = bhid & 7;

    const float m0 = Mp[rowid], m1 = Mp[32768 + rowid];
    const float l0 = Lp[rowid], l1 = Lp[32768 + rowid];
    const float M = fmaxf(m0, m1);
    const float s0 = __expf(m0 - M), s1 = __expf(m1 - M);
    const float inv = 1.f / (l0 * s0 + l1 * s1);
    const f4 o0 = *(const f4*)&Op[((size_t)rowid << 6) + d4];
    const f4 o1 = *(const f4*)&Op[((size_t)(32768 + rowid) << 6) + d4];
    float vals[4] = {
        (o0.x * s0 + o1.x * s1) * inv, (o0.y * s0 + o1.y * s1) * inv,
        (o0.z * s0 + o1.z * s1) * inv, (o0.w * s0 + o1.w * s1) * inv};
    u16x4 hv, lv;
#pragma unroll
    for (int e = 0; e < 4; ++e) {
        hv[e] = f2bf(vals[e]);
        lv[e] = f2bf(vals[e] - bf2f(hv[e]));
    }
    const int d_full = (h << 6) + d4;
    const int dsw = d_full ^ (((s >> 1) & 3) << 3);   // pre-swizzle for gll
    const size_t o = ((size_t)b * SEQ + s) * DM + dsw;
    *(u16x4*)&cth[o] = hv;
    *(u16x4*)&ctl[o] = lv;
}

extern "C" void kernel_launch(void* const* d_in, const int* in_sizes, int n_in,
                              void* d_out, int out_size, void* d_ws, size_t ws_size,
                              hipStream_t stream)
{
    const float* x  = (const float*)d_in[0];
    const float* wq = (const float*)d_in[1];
    const float* bq = (const float*)d_in[2];
    const float* wk = (const float*)d_in[3];
    const float* bk = (const float*)d_in[4];
    const float* wv = (const float*)d_in[5];
    const float* bv = (const float*)d_in[6];
    const float* wo = (const float*)d_in[7];
    const float* bo = (const float*)d_in[8];
    const float* wr = (const float*)d_in[9];
    const float* u  = (const float*)d_in[10];
    const float* vb = (const float*)d_in[11];
    const float* pe = (const float*)d_in[12];
    float* out = (float*)d_out;
    unsigned short* us = (unsigned short*)d_ws;

    unsigned short* xh  = us;                    // 2097152
    unsigned short* xl  = us + 2097152;
    unsigned short* wb  = us + 4194304;          // 5 x (hi 262144 + lo 262144)
    unsigned short* peh = us + 6815744;          // 524288
    unsigned short* pel = us + 7340032;
    unsigned short* qh  = us + 7864320;          // 2097152 each
    unsigned short* ql  = us + 9961472;
    unsigned short* kh  = us + 12058624;
    unsigned short* kl  = us + 14155776;
    unsigned short* vth = us + 16252928;
    unsigned short* vtl = us + 18350080;
    unsigned short* rmh = us + 20447232;         // 524288 each
    unsigned short* rml = us + 20971520;
    unsigned short* cth = us + 21495808;
    unsigned short* ctl = us + 23592960;
    float* rc = (float*)(us + 25690112);         // 8192 f32
    float* Op = (float*)(us + 25706496);         // [2][64*512][64] f32
    float* Mp = Op + 4194304;                    // [2][64*512] f32
    float* Lp = Mp + 65536;

    unsigned short* woh = wb + 3 * 524288;
    unsigned short* wol = woh + 262144;

    dim3 blk(256);
    cvt_all_kernel<<<1920, blk, 0, stream>>>(x, wq, wk, wv, wo, wr,
                                             pe + (size_t)PE_OFF * DM,
                                             xh, xl, wb, peh, pel);
    qkv_rm_kernel<<<832, blk, 0, stream>>>(xh, xl, wb, peh, pel,
                                           bq, bk, bv, u, vb,
                                           qh, ql, kh, kl, vth, vtl,
                                           rmh, rml, rc);
    attn_kernel<<<dim3(8, 2, 64), blk, 0, stream>>>(qh, ql, kh, kl, vth, vtl,
                                                    rmh, rml, rc, Op, Mp, Lp);
    merge_kernel<<<2048, blk, 0, stream>>>(Op, Mp, Lp, cth, ctl);
    out_kernel<<<dim3(8, 32), blk, 0, stream>>>(cth, ctl, woh, wol, bo, out);
}

// Round 16
// 116.978 us; speedup vs baseline: 1.5484x; 1.5484x over previous
//
#include <hip/hip_runtime.h>
#include <math.h>

#define DM 512
#define NH 8
#define DH 64
#define SEQ 512
#define BATCH 8
#define MR 1023
#define PE_OFF 4489

typedef float4 f4;
typedef __attribute__((ext_vector_type(8))) short bf16x8;
typedef __attribute__((ext_vector_type(4))) float f32x4;
typedef __attribute__((ext_vector_type(8))) unsigned short u16x8;
typedef __attribute__((ext_vector_type(4))) unsigned short u16x4;

__device__ __forceinline__ unsigned short f2bf(float f) {
    unsigned x = __float_as_uint(f);
    unsigned r = x + 0x7fffu + ((x >> 16) & 1u);
    return (unsigned short)(r >> 16);
}
__device__ __forceinline__ float bf2f(unsigned short h) {
    return __uint_as_float(((unsigned)h) << 16);
}
__device__ __forceinline__ f32x4 mfma16(bf16x8 a, bf16x8 b, f32x4 c) {
    return __builtin_amdgcn_mfma_f32_16x16x32_bf16(a, b, c, 0, 0, 0);
}
// async global->LDS, 16B per lane, dest = uniform base + lane*16
__device__ __forceinline__ void gll16(const unsigned short* g, unsigned short* l) {
    __builtin_amdgcn_global_load_lds(
        (const __attribute__((address_space(1))) unsigned int*)g,
        (__attribute__((address_space(3))) unsigned int*)l, 16, 0, 0);
}

// ---------------------------------------------------------------------------
// fp32 -> (bf16 hi, bf16 lo), stored PRE-SWIZZLED for gll staging:
// col' = col ^ (((row>>1)&3)<<3)
// ---------------------------------------------------------------------------
__device__ __forceinline__ void cvt8s(const float* __restrict__ src,
                                      unsigned short* __restrict__ hi,
                                      unsigned short* __restrict__ lo, int i) {
    const int row = i >> 9, col = i & 511;
    const int j = (i & ~511) | (col ^ (((row >> 1) & 3) << 3));
    f4 a = *(const f4*)&src[i];
    f4 b = *(const f4*)&src[i + 4];
    float v[8] = {a.x, a.y, a.z, a.w, b.x, b.y, b.z, b.w};
    u16x8 h, l;
#pragma unroll
    for (int e = 0; e < 8; ++e) {
        unsigned short hb = f2bf(v[e]);
        h[e] = hb;
        l[e] = f2bf(v[e] - bf2f(hb));
    }
    *(u16x8*)&hi[j] = h;
    *(u16x8*)&lo[j] = l;
}

__global__ __launch_bounds__(256) void cvt_all_kernel(
    const float* __restrict__ x,
    const float* __restrict__ w0, const float* __restrict__ w1,
    const float* __restrict__ w2, const float* __restrict__ w3,
    const float* __restrict__ w4, const float* __restrict__ pe,
    unsigned short* __restrict__ xh, unsigned short* __restrict__ xl,
    unsigned short* __restrict__ wb,
    unsigned short* __restrict__ peh, unsigned short* __restrict__ pel)
{
    const int bid = blockIdx.x, tid = threadIdx.x;
    if (bid < 1024) {
        cvt8s(x, xh, xl, (bid * 256 + tid) * 8);
    } else if (bid < 1664) {
        const int wsel = (bid - 1024) >> 7;
        const float* src = (wsel == 0) ? w0 : (wsel == 1) ? w1 :
                           (wsel == 2) ? w2 : (wsel == 3) ? w3 : w4;
        unsigned short* hi = wb + (size_t)wsel * 524288;
        cvt8s(src, hi, hi + 262144, (((bid - 1024) & 127) * 256 + tid) * 8);
    } else {
        const int i = ((bid - 1664) * 256 + tid) * 8;
        if (i < 523776) cvt8s(pe, peh, pel, i);
    }
}

// ---------------------------------------------------------------------------
// Split-bf16 GEMM core, 128x64 tile, DOUBLE-BUFFERED gll staging (T3 2-phase):
// issue next K-tile's gll before computing current; one barrier per step.
// Buffers: A = 2 x 128x32, B = 2 x 64x32 (49,152 B total -> 3 blocks/CU).
// ---------------------------------------------------------------------------
__device__ __forceinline__ void gemm_core128(
    const unsigned short* __restrict__ Ah, const unsigned short* __restrict__ Al,
    const unsigned short* __restrict__ Wh, const unsigned short* __restrict__ Wl,
    int m0, int n0, f32x4 acc[4][2],
    unsigned short* LAh, unsigned short* LAl,
    unsigned short* LBh, unsigned short* LBl)
{
    const int tid = threadIdx.x;
    const int lane = tid & 63, wid = tid >> 6;
    const int wm = (wid >> 1) << 6, wn = (wid & 1) << 5;
    const int fr = lane & 15, g = lane >> 4;
    const int crow = lane >> 2;
    const int ccol = (lane & 3) << 3;

#pragma unroll
    for (int i = 0; i < 4; ++i)
#pragma unroll
        for (int j = 0; j < 2; ++j)
            acc[i][j] = (f32x4){0.f, 0.f, 0.f, 0.f};

    const size_t ga1 = (size_t)(m0 + (wid << 4) + crow) * DM + ccol;
    const size_t ga2 = ga1 + (size_t)64 * DM;
    const size_t gb  = (size_t)(n0 + (wid << 4) + crow) * DM + ccol;
    const int lbase = wid << 9;
    const int cswz = (g ^ ((fr >> 1) & 3)) << 3;

    // prologue: stage K-tile 0 into buffer 0
    gll16(Ah + ga1, LAh + lbase);
    gll16(Ah + ga2, LAh + lbase + 2048);
    gll16(Al + ga1, LAl + lbase);
    gll16(Al + ga2, LAl + lbase + 2048);
    gll16(Wh + gb, LBh + lbase);
    gll16(Wl + gb, LBl + lbase);
    __syncthreads();

    int cur = 0;
#pragma unroll
    for (int t = 0; t < 16; ++t) {
        if (t < 15) {                       // issue next tile into other buffer
            const int kn = (t + 1) << 5;
            const int ab = (cur ^ 1) << 12, bb = (cur ^ 1) << 11;
            gll16(Ah + ga1 + kn, LAh + ab + lbase);
            gll16(Ah + ga2 + kn, LAh + ab + lbase + 2048);
            gll16(Al + ga1 + kn, LAl + ab + lbase);
            gll16(Al + ga2 + kn, LAl + ab + lbase + 2048);
            gll16(Wh + gb + kn, LBh + bb + lbase);
            gll16(Wl + gb + kn, LBl + bb + lbase);
        }
        const int ab = cur << 12, bb = cur << 11;
        bf16x8 a_h[4], a_l[4], b_h[2], b_l[2];
#pragma unroll
        for (int mi = 0; mi < 4; ++mi) {
            const int ro = (wm + (mi << 4) + fr) << 5;
            a_h[mi] = *(const bf16x8*)&LAh[ab + ro + cswz];
            a_l[mi] = *(const bf16x8*)&LAl[ab + ro + cswz];
        }
#pragma unroll
        for (int ni = 0; ni < 2; ++ni) {
            const int ro = (wn + (ni << 4) + fr) << 5;
            b_h[ni] = *(const bf16x8*)&LBh[bb + ro + cswz];
            b_l[ni] = *(const bf16x8*)&LBl[bb + ro + cswz];
        }
#pragma unroll
        for (int mi = 0; mi < 4; ++mi)
#pragma unroll
            for (int ni = 0; ni < 2; ++ni) {
                acc[mi][ni] = mfma16(a_h[mi], b_h[ni], acc[mi][ni]);
                acc[mi][ni] = mfma16(a_h[mi], b_l[ni], acc[mi][ni]);
                acc[mi][ni] = mfma16(a_l[mi], b_h[ni], acc[mi][ni]);
            }
        __syncthreads();   // drains next-tile gll + guards buffer reuse
        cur ^= 1;
    }
}

#define GEMM_LDS \
    __shared__ unsigned short LAh[2 * 128 * 32], LAl[2 * 128 * 32]; \
    __shared__ unsigned short LBh[2 * 64 * 32], LBl[2 * 64 * 32];

// ---------------------------------------------------------------------------
// Fused QKV projection + Rm/rcorr. Flat grid 832 (rm blocks first).
// ---------------------------------------------------------------------------
__global__ __launch_bounds__(256) void qkv_rm_kernel(
    const unsigned short* __restrict__ xh, const unsigned short* __restrict__ xl,
    const unsigned short* __restrict__ wb,
    const unsigned short* __restrict__ peh, const unsigned short* __restrict__ pel,
    const float* __restrict__ bq, const float* __restrict__ bk,
    const float* __restrict__ bv, const float* __restrict__ u,
    const float* __restrict__ vb,
    unsigned short* __restrict__ qh, unsigned short* __restrict__ ql,
    unsigned short* __restrict__ kh, unsigned short* __restrict__ kl,
    unsigned short* __restrict__ vth, unsigned short* __restrict__ vtl,
    unsigned short* __restrict__ rmh, unsigned short* __restrict__ rml,
    float* __restrict__ rc)
{
    GEMM_LDS
    const int bid = blockIdx.x;
    const int tid = threadIdx.x, lane = tid & 63, wid = tid >> 6;
    const int wm = (wid >> 1) << 6, wn = (wid & 1) << 5;
    const int fr = lane & 15, g = lane >> 4;

    if (bid < 64) {
        const int n0 = (bid & 7) << 6, m0 = (bid >> 3) << 7;
        const unsigned short* wrh = wb + 4 * 524288;
        const unsigned short* wrl = wrh + 262144;
        f32x4 acc[4][2];
        gemm_core128(peh, pel, wrh, wrl, m0, n0, acc, LAh, LAl, LBh, LBl);

        const int h = n0 >> 6;
        float part[4][4];
        float wgt[2];
#pragma unroll
        for (int ni = 0; ni < 2; ++ni) {
            const int d = wn + (ni << 4) + fr;
            wgt[ni] = vb[(h << 6) + d] - u[(h << 6) + d];
        }
#pragma unroll
        for (int mi = 0; mi < 4; ++mi)
#pragma unroll
            for (int r = 0; r < 4; ++r) part[mi][r] = 0.f;

#pragma unroll
        for (int ni = 0; ni < 2; ++ni) {
            const int n_g = n0 + wn + (ni << 4) + fr;
            const int d = n_g & 63;
#pragma unroll
            for (int mi = 0; mi < 4; ++mi)
#pragma unroll
                for (int r = 0; r < 4; ++r) {
                    const int dd = m0 + wm + (mi << 4) + (g << 2) + r;
                    const float val = acc[mi][ni][r];
                    const size_t o = (((size_t)h << 10) + dd) * DH + d;
                    const unsigned short hb = f2bf(val);
                    rmh[o] = hb;
                    rml[o] = f2bf(val - bf2f(hb));
                    part[mi][r] = fmaf(wgt[ni], val, part[mi][r]);
                }
        }

        __syncthreads();
        float* cbuf = (float*)LAh;
#pragma unroll
        for (int mi = 0; mi < 4; ++mi)
#pragma unroll
            for (int r = 0; r < 4; ++r) {
                float v = part[mi][r];
#pragma unroll
                for (int off = 8; off; off >>= 1) v += __shfl_xor(v, off, 16);
                if (fr == 0)
                    cbuf[((wid & 1) << 7) + wm + (mi << 4) + (g << 2) + r] = v;
            }
        __syncthreads();
        if (tid < 128)
            rc[((size_t)h << 10) + m0 + tid] = cbuf[tid] + cbuf[128 + tid];
        return;
    }

    const int t = bid - 64;
    const int wsel = t >> 8;
    const int rest = t & 255;
    const int n0 = (rest & 7) << 6, m0 = (rest >> 3) << 7;
    const unsigned short* Wh = wb + (size_t)wsel * 524288;
    const unsigned short* Wl = Wh + 262144;
    f32x4 acc[4][2];
    gemm_core128(xh, xl, Wh, Wl, m0, n0, acc, LAh, LAl, LBh, LBl);

    const float* bias = (wsel == 0) ? bq : (wsel == 1) ? bk : bv;

    if (wsel < 2) {
        unsigned short* oh = (wsel == 0) ? qh : kh;
        unsigned short* ol = (wsel == 0) ? ql : kl;
#pragma unroll
        for (int ni = 0; ni < 2; ++ni) {
            const int n_g = n0 + wn + (ni << 4) + fr;
            float bvv = bias[n_g] + ((wsel == 0) ? u[n_g] : 0.f);
            const int h = n_g >> 6, d = n_g & 63;
#pragma unroll
            for (int mi = 0; mi < 4; ++mi)
#pragma unroll
                for (int r = 0; r < 4; ++r) {
                    const int m_g = m0 + wm + (mi << 4) + (g << 2) + r;
                    const int b = m_g >> 9, s = m_g & 511;
                    const float val = acc[mi][ni][r] + bvv;
                    const size_t o = ((size_t)(b * NH + h) * SEQ + s) * DH + d;
                    const unsigned short hb = f2bf(val);
                    oh[o] = hb;
                    ol[o] = f2bf(val - bf2f(hb));
                }
        }
    } else {
#pragma unroll
        for (int ni = 0; ni < 2; ++ni) {
            const int n_g = n0 + wn + (ni << 4) + fr;
            const float bvv = bias[n_g];
            const int h = n_g >> 6, d = n_g & 63;
#pragma unroll
            for (int mi = 0; mi < 4; ++mi) {
                const int m_b = m0 + wm + (mi << 4) + (g << 2);
                const int b = m_b >> 9, s = m_b & 511;
                u16x4 hv, lv;
#pragma unroll
                for (int r = 0; r < 4; ++r) {
                    const float val = acc[mi][ni][r] + bvv;
                    hv[r] = f2bf(val);
                    lv[r] = f2bf(val - bf2f(hv[r]));
                }
                const size_t o = ((size_t)(b * NH + h) * DH + d) * SEQ + s;
                *(u16x4*)&vth[o] = hv;
                *(u16x4*)&vtl[o] = lv;
            }
        }
    }
}

// out = ctx @ wo^T + bo  (f32 out). grid (8, 32).
__global__ __launch_bounds__(256) void out_kernel(
    const unsigned short* __restrict__ cth, const unsigned short* __restrict__ ctl,
    const unsigned short* __restrict__ woh, const unsigned short* __restrict__ wol,
    const float* __restrict__ bo, float* __restrict__ out)
{
    GEMM_LDS
    const int n0 = blockIdx.x << 6, m0 = blockIdx.y << 7;
    f32x4 acc[4][2];
    gemm_core128(cth, ctl, woh, wol, m0, n0, acc, LAh, LAl, LBh, LBl);

    const int tid = threadIdx.x, lane = tid & 63, wid = tid >> 6;
    const int wm = (wid >> 1) << 6, wn = (wid & 1) << 5;
    const int fr = lane & 15, g = lane >> 4;
#pragma unroll
    for (int ni = 0; ni < 2; ++ni) {
        const int n_g = n0 + wn + (ni << 4) + fr;
        const float bvv = bo[n_g];
#pragma unroll
        for (int mi = 0; mi < 4; ++mi)
#pragma unroll
            for (int r = 0; r < 4; ++r) {
                const int m_g = m0 + wm + (mi << 4) + (g << 2) + r;
                out[(size_t)m_g * DM + n_g] = acc[mi][ni][r] + bvv;
            }
    }
}

// ---------------------------------------------------------------------------
// MFMA flash attention — R14 structure verbatim (57.0 us measured): K+V
// LDS-staged, T14 register prefetch, grid 512, Pt f32, 3-MFMA PV, ctx stored
// pre-swizzled for out_kernel's gll.
// ---------------------------------------------------------------------------
__global__ __launch_bounds__(256) void attn_kernel(
    const unsigned short* __restrict__ qh_g, const unsigned short* __restrict__ ql_g,
    const unsigned short* __restrict__ kh_g, const unsigned short* __restrict__ kl_g,
    const unsigned short* __restrict__ vh_g, const unsigned short* __restrict__ vl_g,
    const unsigned short* __restrict__ rmh, const unsigned short* __restrict__ rml,
    const float* __restrict__ rc,
    unsigned short* __restrict__ cth, unsigned short* __restrict__ ctl)
{
    __shared__ unsigned short Kh[64][72], Kl[64][72], Vh[64][72], Vl[64][72];
    __shared__ unsigned short Pdd[4][16][84];
    __shared__ float Pt[4][16][68];

    const int tid = threadIdx.x;
    const int lane = tid & 63, wid = tid >> 6;
    const int g = lane >> 4, c = lane & 15;
    const int i0 = blockIdx.x << 6;
    const int h = blockIdx.y, b = blockIdx.z;
    const int R0 = i0 + (wid << 4);
    const size_t bh = (size_t)(b * NH + h) * (SEQ * DH);

    const int srow = tid >> 3;
    const int sch = (tid & 7) << 3;

    bf16x8 qhf[2], qlf[2];
#pragma unroll
    for (int ks = 0; ks < 2; ++ks) {
        const size_t qo = bh + (size_t)(R0 + c) * DH + (ks << 5) + (g << 3);
        qhf[ks] = *(const bf16x8*)&qh_g[qo];
        qlf[ks] = *(const bf16x8*)&ql_g[qo];
    }

    f32x4 Oacc[4];
#pragma unroll
    for (int nf = 0; nf < 4; ++nf) Oacc[nf] = (f32x4){0.f, 0.f, 0.f, 0.f};
    float m_r[4] = {-3e38f, -3e38f, -3e38f, -3e38f};
    float l_r[4] = {0.f, 0.f, 0.f, 0.f};

    const float* rch = rc + (h << 10);
    const unsigned short* rmhh = rmh + ((size_t)h << 16);
    const unsigned short* rmlh = rml + ((size_t)h << 16);

    u16x8 p0, p1, p2, p3, p4, p5, p6, p7;
    {
        const size_t kb = bh + (size_t)srow * DH + sch;
        p0 = *(const u16x8*)&kh_g[kb];
        p1 = *(const u16x8*)&kh_g[kb + 32 * DH];
        p2 = *(const u16x8*)&kl_g[kb];
        p3 = *(const u16x8*)&kl_g[kb + 32 * DH];
        const size_t vb_ = bh + (size_t)srow * SEQ + sch;
        p4 = *(const u16x8*)&vh_g[vb_];
        p5 = *(const u16x8*)&vh_g[vb_ + 32 * SEQ];
        p6 = *(const u16x8*)&vl_g[vb_];
        p7 = *(const u16x8*)&vl_g[vb_ + 32 * SEQ];
    }

    for (int jt = 0; jt < 8; ++jt) {
        const int j0 = jt << 6;
        __syncthreads();
        *(u16x8*)&Kh[srow][sch] = p0;
        *(u16x8*)&Kh[srow + 32][sch] = p1;
        *(u16x8*)&Kl[srow][sch] = p2;
        *(u16x8*)&Kl[srow + 32][sch] = p3;
        *(u16x8*)&Vh[srow][sch] = p4;
        *(u16x8*)&Vh[srow + 32][sch] = p5;
        *(u16x8*)&Vl[srow][sch] = p6;
        *(u16x8*)&Vl[srow + 32][sch] = p7;
        __syncthreads();
        if (jt < 7) {
            const int jn = j0 + 64;
            const size_t kb = bh + (size_t)(jn + srow) * DH + sch;
            p0 = *(const u16x8*)&kh_g[kb];
            p1 = *(const u16x8*)&kh_g[kb + 32 * DH];
            p2 = *(const u16x8*)&kl_g[kb];
            p3 = *(const u16x8*)&kl_g[kb + 32 * DH];
            const size_t vb_ = bh + (size_t)srow * SEQ + jn + sch;
            p4 = *(const u16x8*)&vh_g[vb_];
            p5 = *(const u16x8*)&vh_g[vb_ + 32 * SEQ];
            p6 = *(const u16x8*)&vl_g[vb_];
            p7 = *(const u16x8*)&vl_g[vb_ + 32 * SEQ];
        }

        __builtin_amdgcn_s_setprio(1);
        f32x4 accs[4];
#pragma unroll
        for (int nf = 0; nf < 4; ++nf) accs[nf] = (f32x4){0.f, 0.f, 0.f, 0.f};
#pragma unroll
        for (int ks = 0; ks < 2; ++ks)
#pragma unroll
            for (int nf = 0; nf < 4; ++nf) {
                bf16x8 b_h = *(const bf16x8*)&Kh[(nf << 4) + c][(ks << 5) + (g << 3)];
                bf16x8 b_l = *(const bf16x8*)&Kl[(nf << 4) + c][(ks << 5) + (g << 3)];
                accs[nf] = mfma16(qhf[ks], b_h, accs[nf]);
                accs[nf] = mfma16(qhf[ks], b_l, accs[nf]);
                accs[nf] = mfma16(qlf[ks], b_h, accs[nf]);
            }

        const int base_g = j0 - R0 + 496;
#pragma unroll
        for (int f = 0; f < 5; ++f) {
            f32x4 ap = (f32x4){0.f, 0.f, 0.f, 0.f};
#pragma unroll
            for (int ks = 0; ks < 2; ++ks) {
                const size_t ro = (size_t)(base_g + (f << 4) + c) * DH
                                + (ks << 5) + (g << 3);
                bf16x8 b_h = *(const bf16x8*)&rmhh[ro];
                bf16x8 b_l = *(const bf16x8*)&rmlh[ro];
                ap = mfma16(qhf[ks], b_h, ap);
                ap = mfma16(qhf[ks], b_l, ap);
                ap = mfma16(qlf[ks], b_h, ap);
            }
            const float rcv = rch[base_g + (f << 4) + c];
#pragma unroll
            for (int r = 0; r < 4; ++r)
                Pdd[wid][(g << 2) + r][(f << 4) + c] = f2bf(ap[r] + rcv);
        }
        __builtin_amdgcn_s_setprio(0);

#pragma unroll
        for (int r = 0; r < 4; ++r) {
            const int irow = (g << 2) + r;
            float sc[4];
#pragma unroll
            for (int nf = 0; nf < 4; ++nf) {
                const int ddl = (nf << 4) + c - irow + 15;
                sc[nf] = (accs[nf][r] + bf2f(Pdd[wid][irow][ddl])) * 0.125f;
            }
            float mt = fmaxf(fmaxf(sc[0], sc[1]), fmaxf(sc[2], sc[3]));
#pragma unroll
            for (int off = 8; off; off >>= 1) mt = fmaxf(mt, __shfl_xor(mt, off, 16));
            const float mn = fmaxf(m_r[r], mt);
            const float alpha = __expf(m_r[r] - mn);
            m_r[r] = mn;
            float rs = 0.f;
#pragma unroll
            for (int nf = 0; nf < 4; ++nf) {
                const float p = __expf(sc[nf] - mn);
                Pt[wid][irow][(nf << 4) + c] = p;
                rs += p;
            }
#pragma unroll
            for (int off = 8; off; off >>= 1) rs += __shfl_xor(rs, off, 16);
            l_r[r] = l_r[r] * alpha + rs;
#pragma unroll
            for (int nf = 0; nf < 4; ++nf) Oacc[nf][r] *= alpha;
        }

        __builtin_amdgcn_s_setprio(1);
#pragma unroll
        for (int ks = 0; ks < 2; ++ks) {
            f4 pv0 = *(const f4*)&Pt[wid][c][(ks << 5) + (g << 3)];
            f4 pv1 = *(const f4*)&Pt[wid][c][(ks << 5) + (g << 3) + 4];
            float pv[8] = {pv0.x, pv0.y, pv0.z, pv0.w, pv1.x, pv1.y, pv1.z, pv1.w};
            bf16x8 ph, pl;
#pragma unroll
            for (int e = 0; e < 8; ++e) {
                const unsigned short hb = f2bf(pv[e]);
                ph[e] = (short)hb;
                pl[e] = (short)f2bf(pv[e] - bf2f(hb));
            }
#pragma unroll
            for (int nf = 0; nf < 4; ++nf) {
                bf16x8 v_h = *(const bf16x8*)&Vh[(nf << 4) + c][(ks << 5) + (g << 3)];
                bf16x8 v_l = *(const bf16x8*)&Vl[(nf << 4) + c][(ks << 5) + (g << 3)];
                Oacc[nf] = mfma16(ph, v_h, Oacc[nf]);
                Oacc[nf] = mfma16(ph, v_l, Oacc[nf]);
                Oacc[nf] = mfma16(pl, v_h, Oacc[nf]);
            }
        }
        __builtin_amdgcn_s_setprio(0);
    }

    float inv[4];
#pragma unroll
    for (int r = 0; r < 4; ++r) inv[r] = 1.f / l_r[r];
#pragma unroll
    for (int nf = 0; nf < 4; ++nf)
#pragma unroll
        for (int r = 0; r < 4; ++r) {
            const float val = Oacc[nf][r] * inv[r];
            const int sr_ = (g << 2) + r;
            const int s = R0 + sr_;
            const int d = (h << 6) + (nf << 4) + c;
            const int dsw = d ^ (((sr_ >> 1) & 3) << 3);
            const size_t o = ((size_t)(b * SEQ) + s) * DM + dsw;
            const unsigned short hb = f2bf(val);
            cth[o] = hb;
            ctl[o] = f2bf(val - bf2f(hb));
        }
}

extern "C" void kernel_launch(void* const* d_in, const int* in_sizes, int n_in,
                              void* d_out, int out_size, void* d_ws, size_t ws_size,
                              hipStream_t stream)
{
    const float* x  = (const float*)d_in[0];
    const float* wq = (const float*)d_in[1];
    const float* bq = (const float*)d_in[2];
    const float* wk = (const float*)d_in[3];
    const float* bk = (const float*)d_in[4];
    const float* wv = (const float*)d_in[5];
    const float* bv = (const float*)d_in[6];
    const float* wo = (const float*)d_in[7];
    const float* bo = (const float*)d_in[8];
    const float* wr = (const float*)d_in[9];
    const float* u  = (const float*)d_in[10];
    const float* vb = (const float*)d_in[11];
    const float* pe = (const float*)d_in[12];
    float* out = (float*)d_out;
    unsigned short* us = (unsigned short*)d_ws;

    unsigned short* xh  = us;                    // 2097152
    unsigned short* xl  = us + 2097152;
    unsigned short* wb  = us + 4194304;          // 5 x (hi 262144 + lo 262144)
    unsigned short* peh = us + 6815744;          // 524288
    unsigned short* pel = us + 7340032;
    unsigned short* qh  = us + 7864320;          // 2097152 each
    unsigned short* ql  = us + 9961472;
    unsigned short* kh  = us + 12058624;
    unsigned short* kl  = us + 14155776;
    unsigned short* vth = us + 16252928;
    unsigned short* vtl = us + 18350080;
    unsigned short* rmh = us + 20447232;         // 524288 each
    unsigned short* rml = us + 20971520;
    unsigned short* cth = us + 21495808;
    unsigned short* ctl = us + 23592960;
    float* rc = (float*)(us + 25690112);         // 8192 f32

    unsigned short* woh = wb + 3 * 524288;
    unsigned short* wol = woh + 262144;

    dim3 blk(256);
    cvt_all_kernel<<<1920, blk, 0, stream>>>(x, wq, wk, wv, wo, wr,
                                             pe + (size_t)PE_OFF * DM,
                                             xh, xl, wb, peh, pel);
    qkv_rm_kernel<<<832, blk, 0, stream>>>(xh, xl, wb, peh, pel,
                                           bq, bk, bv, u, vb,
                                           qh, ql, kh, kl, vth, vtl,
                                           rmh, rml, rc);
    attn_kernel<<<dim3(8, 8, 8), blk, 0, stream>>>(qh, ql, kh, kl, vth, vtl,
                                                   rmh, rml, rc, cth, ctl);
    out_kernel<<<dim3(8, 32), blk, 0, stream>>>(cth, ctl, woh, wol, bo, out);
}

// Round 17
// 114.871 us; speedup vs baseline: 1.5768x; 1.0183x over previous
//
#include <hip/hip_runtime.h>
#include <math.h>

#define DM 512
#define NH 8
#define DH 64
#define SEQ 512
#define BATCH 8
#define MR 1023
#define PE_OFF 4489

typedef float4 f4;
typedef __attribute__((ext_vector_type(8))) short bf16x8;
typedef __attribute__((ext_vector_type(4))) float f32x4;
typedef __attribute__((ext_vector_type(8))) unsigned short u16x8;
typedef __attribute__((ext_vector_type(4))) unsigned short u16x4;

__device__ __forceinline__ unsigned short f2bf(float f) {
    unsigned x = __float_as_uint(f);
    unsigned r = x + 0x7fffu + ((x >> 16) & 1u);
    return (unsigned short)(r >> 16);
}
__device__ __forceinline__ float bf2f(unsigned short h) {
    return __uint_as_float(((unsigned)h) << 16);
}
__device__ __forceinline__ f32x4 mfma16(bf16x8 a, bf16x8 b, f32x4 c) {
    return __builtin_amdgcn_mfma_f32_16x16x32_bf16(a, b, c, 0, 0, 0);
}
// async global->LDS, 16B per lane, dest = uniform base + lane*16
__device__ __forceinline__ void gll16(const unsigned short* g, unsigned short* l) {
    __builtin_amdgcn_global_load_lds(
        (const __attribute__((address_space(1))) unsigned int*)g,
        (__attribute__((address_space(3))) unsigned int*)l, 16, 0, 0);
}

// ---------------------------------------------------------------------------
// fp32 -> (bf16 hi, bf16 lo), stored PRE-SWIZZLED for gll staging:
// col' = col ^ (((row>>1)&3)<<3)
// ---------------------------------------------------------------------------
__device__ __forceinline__ void cvt8s(const float* __restrict__ src,
                                      unsigned short* __restrict__ hi,
                                      unsigned short* __restrict__ lo, int i) {
    const int row = i >> 9, col = i & 511;
    const int j = (i & ~511) | (col ^ (((row >> 1) & 3) << 3));
    f4 a = *(const f4*)&src[i];
    f4 b = *(const f4*)&src[i + 4];
    float v[8] = {a.x, a.y, a.z, a.w, b.x, b.y, b.z, b.w};
    u16x8 h, l;
#pragma unroll
    for (int e = 0; e < 8; ++e) {
        unsigned short hb = f2bf(v[e]);
        h[e] = hb;
        l[e] = f2bf(v[e] - bf2f(hb));
    }
    *(u16x8*)&hi[j] = h;
    *(u16x8*)&lo[j] = l;
}

__global__ __launch_bounds__(256) void cvt_all_kernel(
    const float* __restrict__ x,
    const float* __restrict__ w0, const float* __restrict__ w1,
    const float* __restrict__ w2, const float* __restrict__ w3,
    const float* __restrict__ w4, const float* __restrict__ pe,
    unsigned short* __restrict__ xh, unsigned short* __restrict__ xl,
    unsigned short* __restrict__ wb,
    unsigned short* __restrict__ peh, unsigned short* __restrict__ pel)
{
    const int bid = blockIdx.x, tid = threadIdx.x;
    if (bid < 1024) {
        cvt8s(x, xh, xl, (bid * 256 + tid) * 8);
    } else if (bid < 1664) {
        const int wsel = (bid - 1024) >> 7;
        const float* src = (wsel == 0) ? w0 : (wsel == 1) ? w1 :
                           (wsel == 2) ? w2 : (wsel == 3) ? w3 : w4;
        unsigned short* hi = wb + (size_t)wsel * 524288;
        cvt8s(src, hi, hi + 262144, (((bid - 1024) & 127) * 256 + tid) * 8);
    } else {
        const int i = ((bid - 1664) * 256 + tid) * 8;
        if (i < 523776) cvt8s(pe, peh, pel, i);
    }
}

// ---------------------------------------------------------------------------
// Split-bf16 GEMM core, 128x64 tile, double-buffered gll staging.
// FULL=1: 3-term (ahbh+ahbl+albh). FULL=0: 2-term (ahbh+ahbl), A-lo unused —
// for error-tolerant outputs (q,k: softmax smooths ~1e-3 relative A error).
// ---------------------------------------------------------------------------
template<int FULL>
__device__ __forceinline__ void gemm_core128(
    const unsigned short* __restrict__ Ah, const unsigned short* __restrict__ Al,
    const unsigned short* __restrict__ Wh, const unsigned short* __restrict__ Wl,
    int m0, int n0, f32x4 acc[4][2],
    unsigned short* LAh, unsigned short* LAl,
    unsigned short* LBh, unsigned short* LBl)
{
    const int tid = threadIdx.x;
    const int lane = tid & 63, wid = tid >> 6;
    const int wm = (wid >> 1) << 6, wn = (wid & 1) << 5;
    const int fr = lane & 15, g = lane >> 4;
    const int crow = lane >> 2;
    const int ccol = (lane & 3) << 3;

#pragma unroll
    for (int i = 0; i < 4; ++i)
#pragma unroll
        for (int j = 0; j < 2; ++j)
            acc[i][j] = (f32x4){0.f, 0.f, 0.f, 0.f};

    const size_t ga1 = (size_t)(m0 + (wid << 4) + crow) * DM + ccol;
    const size_t ga2 = ga1 + (size_t)64 * DM;
    const size_t gb  = (size_t)(n0 + (wid << 4) + crow) * DM + ccol;
    const int lbase = wid << 9;
    const int cswz = (g ^ ((fr >> 1) & 3)) << 3;

    // prologue: stage K-tile 0 into buffer 0
    gll16(Ah + ga1, LAh + lbase);
    gll16(Ah + ga2, LAh + lbase + 2048);
    if (FULL) {
        gll16(Al + ga1, LAl + lbase);
        gll16(Al + ga2, LAl + lbase + 2048);
    }
    gll16(Wh + gb, LBh + lbase);
    gll16(Wl + gb, LBl + lbase);
    __syncthreads();

    int cur = 0;
#pragma unroll
    for (int t = 0; t < 16; ++t) {
        if (t < 15) {                       // issue next tile into other buffer
            const int kn = (t + 1) << 5;
            const int ab = (cur ^ 1) << 12, bb = (cur ^ 1) << 11;
            gll16(Ah + ga1 + kn, LAh + ab + lbase);
            gll16(Ah + ga2 + kn, LAh + ab + lbase + 2048);
            if (FULL) {
                gll16(Al + ga1 + kn, LAl + ab + lbase);
                gll16(Al + ga2 + kn, LAl + ab + lbase + 2048);
            }
            gll16(Wh + gb + kn, LBh + bb + lbase);
            gll16(Wl + gb + kn, LBl + bb + lbase);
        }
        const int ab = cur << 12, bb = cur << 11;
        bf16x8 a_h[4], a_l[4], b_h[2], b_l[2];
#pragma unroll
        for (int mi = 0; mi < 4; ++mi) {
            const int ro = (wm + (mi << 4) + fr) << 5;
            a_h[mi] = *(const bf16x8*)&LAh[ab + ro + cswz];
            if (FULL) a_l[mi] = *(const bf16x8*)&LAl[ab + ro + cswz];
        }
#pragma unroll
        for (int ni = 0; ni < 2; ++ni) {
            const int ro = (wn + (ni << 4) + fr) << 5;
            b_h[ni] = *(const bf16x8*)&LBh[bb + ro + cswz];
            b_l[ni] = *(const bf16x8*)&LBl[bb + ro + cswz];
        }
#pragma unroll
        for (int mi = 0; mi < 4; ++mi)
#pragma unroll
            for (int ni = 0; ni < 2; ++ni) {
                acc[mi][ni] = mfma16(a_h[mi], b_h[ni], acc[mi][ni]);
                acc[mi][ni] = mfma16(a_h[mi], b_l[ni], acc[mi][ni]);
                if (FULL) acc[mi][ni] = mfma16(a_l[mi], b_h[ni], acc[mi][ni]);
            }
        __syncthreads();
        cur ^= 1;
    }
}

#define GEMM_LDS \
    __shared__ unsigned short LAh[2 * 128 * 32], LAl[2 * 128 * 32]; \
    __shared__ unsigned short LBh[2 * 64 * 32], LBl[2 * 64 * 32];

// ---------------------------------------------------------------------------
// Fused QKV projection + Rm/rcorr. Flat grid 832 (rm blocks first).
// q,k: 2-term GEMM; v, rm: 3-term.
// ---------------------------------------------------------------------------
__global__ __launch_bounds__(256) void qkv_rm_kernel(
    const unsigned short* __restrict__ xh, const unsigned short* __restrict__ xl,
    const unsigned short* __restrict__ wb,
    const unsigned short* __restrict__ peh, const unsigned short* __restrict__ pel,
    const float* __restrict__ bq, const float* __restrict__ bk,
    const float* __restrict__ bv, const float* __restrict__ u,
    const float* __restrict__ vb,
    unsigned short* __restrict__ qh, unsigned short* __restrict__ ql,
    unsigned short* __restrict__ kh, unsigned short* __restrict__ kl,
    unsigned short* __restrict__ vth, unsigned short* __restrict__ vtl,
    unsigned short* __restrict__ rmh, unsigned short* __restrict__ rml,
    float* __restrict__ rc)
{
    GEMM_LDS
    const int bid = blockIdx.x;
    const int tid = threadIdx.x, lane = tid & 63, wid = tid >> 6;
    const int wm = (wid >> 1) << 6, wn = (wid & 1) << 5;
    const int fr = lane & 15, g = lane >> 4;

    if (bid < 64) {
        const int n0 = (bid & 7) << 6, m0 = (bid >> 3) << 7;
        const unsigned short* wrh = wb + 4 * 524288;
        const unsigned short* wrl = wrh + 262144;
        f32x4 acc[4][2];
        gemm_core128<1>(peh, pel, wrh, wrl, m0, n0, acc, LAh, LAl, LBh, LBl);

        const int h = n0 >> 6;
        float part[4][4];
        float wgt[2];
#pragma unroll
        for (int ni = 0; ni < 2; ++ni) {
            const int d = wn + (ni << 4) + fr;
            wgt[ni] = vb[(h << 6) + d] - u[(h << 6) + d];
        }
#pragma unroll
        for (int mi = 0; mi < 4; ++mi)
#pragma unroll
            for (int r = 0; r < 4; ++r) part[mi][r] = 0.f;

#pragma unroll
        for (int ni = 0; ni < 2; ++ni) {
            const int n_g = n0 + wn + (ni << 4) + fr;
            const int d = n_g & 63;
#pragma unroll
            for (int mi = 0; mi < 4; ++mi)
#pragma unroll
                for (int r = 0; r < 4; ++r) {
                    const int dd = m0 + wm + (mi << 4) + (g << 2) + r;
                    const float val = acc[mi][ni][r];
                    const size_t o = (((size_t)h << 10) + dd) * DH + d;
                    const unsigned short hb = f2bf(val);
                    rmh[o] = hb;
                    rml[o] = f2bf(val - bf2f(hb));
                    part[mi][r] = fmaf(wgt[ni], val, part[mi][r]);
                }
        }

        __syncthreads();
        float* cbuf = (float*)LAh;
#pragma unroll
        for (int mi = 0; mi < 4; ++mi)
#pragma unroll
            for (int r = 0; r < 4; ++r) {
                float v = part[mi][r];
#pragma unroll
                for (int off = 8; off; off >>= 1) v += __shfl_xor(v, off, 16);
                if (fr == 0)
                    cbuf[((wid & 1) << 7) + wm + (mi << 4) + (g << 2) + r] = v;
            }
        __syncthreads();
        if (tid < 128)
            rc[((size_t)h << 10) + m0 + tid] = cbuf[tid] + cbuf[128 + tid];
        return;
    }

    const int t = bid - 64;
    const int wsel = t >> 8;
    const int rest = t & 255;
    const int n0 = (rest & 7) << 6, m0 = (rest >> 3) << 7;
    const unsigned short* Wh = wb + (size_t)wsel * 524288;
    const unsigned short* Wl = Wh + 262144;
    f32x4 acc[4][2];
    if (wsel < 2)
        gemm_core128<0>(xh, xl, Wh, Wl, m0, n0, acc, LAh, LAl, LBh, LBl);
    else
        gemm_core128<1>(xh, xl, Wh, Wl, m0, n0, acc, LAh, LAl, LBh, LBl);

    const float* bias = (wsel == 0) ? bq : (wsel == 1) ? bk : bv;

    if (wsel < 2) {
        unsigned short* oh = (wsel == 0) ? qh : kh;
        unsigned short* ol = (wsel == 0) ? ql : kl;
#pragma unroll
        for (int ni = 0; ni < 2; ++ni) {
            const int n_g = n0 + wn + (ni << 4) + fr;
            float bvv = bias[n_g] + ((wsel == 0) ? u[n_g] : 0.f);
            const int h = n_g >> 6, d = n_g & 63;
#pragma unroll
            for (int mi = 0; mi < 4; ++mi)
#pragma unroll
                for (int r = 0; r < 4; ++r) {
                    const int m_g = m0 + wm + (mi << 4) + (g << 2) + r;
                    const int b = m_g >> 9, s = m_g & 511;
                    const float val = acc[mi][ni][r] + bvv;
                    const size_t o = ((size_t)(b * NH + h) * SEQ + s) * DH + d;
                    const unsigned short hb = f2bf(val);
                    oh[o] = hb;
                    ol[o] = f2bf(val - bf2f(hb));
                }
        }
    } else {
#pragma unroll
        for (int ni = 0; ni < 2; ++ni) {
            const int n_g = n0 + wn + (ni << 4) + fr;
            const float bvv = bias[n_g];
            const int h = n_g >> 6, d = n_g & 63;
#pragma unroll
            for (int mi = 0; mi < 4; ++mi) {
                const int m_b = m0 + wm + (mi << 4) + (g << 2);
                const int b = m_b >> 9, s = m_b & 511;
                u16x4 hv, lv;
#pragma unroll
                for (int r = 0; r < 4; ++r) {
                    const float val = acc[mi][ni][r] + bvv;
                    hv[r] = f2bf(val);
                    lv[r] = f2bf(val - bf2f(hv[r]));
                }
                const size_t o = ((size_t)(b * NH + h) * DH + d) * SEQ + s;
                *(u16x4*)&vth[o] = hv;
                *(u16x4*)&vtl[o] = lv;
            }
        }
    }
}

// out = ctx @ wo^T + bo  (f32 out). grid (8, 32). 3-term.
__global__ __launch_bounds__(256) void out_kernel(
    const unsigned short* __restrict__ cth, const unsigned short* __restrict__ ctl,
    const unsigned short* __restrict__ woh, const unsigned short* __restrict__ wol,
    const float* __restrict__ bo, float* __restrict__ out)
{
    GEMM_LDS
    const int n0 = blockIdx.x << 6, m0 = blockIdx.y << 7;
    f32x4 acc[4][2];
    gemm_core128<1>(cth, ctl, woh, wol, m0, n0, acc, LAh, LAl, LBh, LBl);

    const int tid = threadIdx.x, lane = tid & 63, wid = tid >> 6;
    const int wm = (wid >> 1) << 6, wn = (wid & 1) << 5;
    const int fr = lane & 15, g = lane >> 4;
#pragma unroll
    for (int ni = 0; ni < 2; ++ni) {
        const int n_g = n0 + wn + (ni << 4) + fr;
        const float bvv = bo[n_g];
#pragma unroll
        for (int mi = 0; mi < 4; ++mi)
#pragma unroll
            for (int r = 0; r < 4; ++r) {
                const int m_g = m0 + wm + (mi << 4) + (g << 2) + r;
                out[(size_t)m_g * DM + n_g] = acc[mi][ni][r] + bvv;
            }
    }
}

// ---------------------------------------------------------------------------
// MFMA flash attention — R14 structure verbatim (57.0 us measured).
// ---------------------------------------------------------------------------
__global__ __launch_bounds__(256) void attn_kernel(
    const unsigned short* __restrict__ qh_g, const unsigned short* __restrict__ ql_g,
    const unsigned short* __restrict__ kh_g, const unsigned short* __restrict__ kl_g,
    const unsigned short* __restrict__ vh_g, const unsigned short* __restrict__ vl_g,
    const unsigned short* __restrict__ rmh, const unsigned short* __restrict__ rml,
    const float* __restrict__ rc,
    unsigned short* __restrict__ cth, unsigned short* __restrict__ ctl)
{
    __shared__ unsigned short Kh[64][72], Kl[64][72], Vh[64][72], Vl[64][72];
    __shared__ unsigned short Pdd[4][16][84];
    __shared__ float Pt[4][16][68];

    const int tid = threadIdx.x;
    const int lane = tid & 63, wid = tid >> 6;
    const int g = lane >> 4, c = lane & 15;
    const int i0 = blockIdx.x << 6;
    const int h = blockIdx.y, b = blockIdx.z;
    const int R0 = i0 + (wid << 4);
    const size_t bh = (size_t)(b * NH + h) * (SEQ * DH);

    const int srow = tid >> 3;
    const int sch = (tid & 7) << 3;

    bf16x8 qhf[2], qlf[2];
#pragma unroll
    for (int ks = 0; ks < 2; ++ks) {
        const size_t qo = bh + (size_t)(R0 + c) * DH + (ks << 5) + (g << 3);
        qhf[ks] = *(const bf16x8*)&qh_g[qo];
        qlf[ks] = *(const bf16x8*)&ql_g[qo];
    }

    f32x4 Oacc[4];
#pragma unroll
    for (int nf = 0; nf < 4; ++nf) Oacc[nf] = (f32x4){0.f, 0.f, 0.f, 0.f};
    float m_r[4] = {-3e38f, -3e38f, -3e38f, -3e38f};
    float l_r[4] = {0.f, 0.f, 0.f, 0.f};

    const float* rch = rc + (h << 10);
    const unsigned short* rmhh = rmh + ((size_t)h << 16);
    const unsigned short* rmlh = rml + ((size_t)h << 16);

    u16x8 p0, p1, p2, p3, p4, p5, p6, p7;
    {
        const size_t kb = bh + (size_t)srow * DH + sch;
        p0 = *(const u16x8*)&kh_g[kb];
        p1 = *(const u16x8*)&kh_g[kb + 32 * DH];
        p2 = *(const u16x8*)&kl_g[kb];
        p3 = *(const u16x8*)&kl_g[kb + 32 * DH];
        const size_t vb_ = bh + (size_t)srow * SEQ + sch;
        p4 = *(const u16x8*)&vh_g[vb_];
        p5 = *(const u16x8*)&vh_g[vb_ + 32 * SEQ];
        p6 = *(const u16x8*)&vl_g[vb_];
        p7 = *(const u16x8*)&vl_g[vb_ + 32 * SEQ];
    }

    for (int jt = 0; jt < 8; ++jt) {
        const int j0 = jt << 6;
        __syncthreads();
        *(u16x8*)&Kh[srow][sch] = p0;
        *(u16x8*)&Kh[srow + 32][sch] = p1;
        *(u16x8*)&Kl[srow][sch] = p2;
        *(u16x8*)&Kl[srow + 32][sch] = p3;
        *(u16x8*)&Vh[srow][sch] = p4;
        *(u16x8*)&Vh[srow + 32][sch] = p5;
        *(u16x8*)&Vl[srow][sch] = p6;
        *(u16x8*)&Vl[srow + 32][sch] = p7;
        __syncthreads();
        if (jt < 7) {
            const int jn = j0 + 64;
            const size_t kb = bh + (size_t)(jn + srow) * DH + sch;
            p0 = *(const u16x8*)&kh_g[kb];
            p1 = *(const u16x8*)&kh_g[kb + 32 * DH];
            p2 = *(const u16x8*)&kl_g[kb];
            p3 = *(const u16x8*)&kl_g[kb + 32 * DH];
            const size_t vb_ = bh + (size_t)srow * SEQ + jn + sch;
            p4 = *(const u16x8*)&vh_g[vb_];
            p5 = *(const u16x8*)&vh_g[vb_ + 32 * SEQ];
            p6 = *(const u16x8*)&vl_g[vb_];
            p7 = *(const u16x8*)&vl_g[vb_ + 32 * SEQ];
        }

        __builtin_amdgcn_s_setprio(1);
        f32x4 accs[4];
#pragma unroll
        for (int nf = 0; nf < 4; ++nf) accs[nf] = (f32x4){0.f, 0.f, 0.f, 0.f};
#pragma unroll
        for (int ks = 0; ks < 2; ++ks)
#pragma unroll
            for (int nf = 0; nf < 4; ++nf) {
                bf16x8 b_h = *(const bf16x8*)&Kh[(nf << 4) + c][(ks << 5) + (g << 3)];
                bf16x8 b_l = *(const bf16x8*)&Kl[(nf << 4) + c][(ks << 5) + (g << 3)];
                accs[nf] = mfma16(qhf[ks], b_h, accs[nf]);
                accs[nf] = mfma16(qhf[ks], b_l, accs[nf]);
                accs[nf] = mfma16(qlf[ks], b_h, accs[nf]);
            }

        const int base_g = j0 - R0 + 496;
#pragma unroll
        for (int f = 0; f < 5; ++f) {
            f32x4 ap = (f32x4){0.f, 0.f, 0.f, 0.f};
#pragma unroll
            for (int ks = 0; ks < 2; ++ks) {
                const size_t ro = (size_t)(base_g + (f << 4) + c) * DH
                                + (ks << 5) + (g << 3);
                bf16x8 b_h = *(const bf16x8*)&rmhh[ro];
                bf16x8 b_l = *(const bf16x8*)&rmlh[ro];
                ap = mfma16(qhf[ks], b_h, ap);
                ap = mfma16(qhf[ks], b_l, ap);
                ap = mfma16(qlf[ks], b_h, ap);
            }
            const float rcv = rch[base_g + (f << 4) + c];
#pragma unroll
            for (int r = 0; r < 4; ++r)
                Pdd[wid][(g << 2) + r][(f << 4) + c] = f2bf(ap[r] + rcv);
        }
        __builtin_amdgcn_s_setprio(0);

#pragma unroll
        for (int r = 0; r < 4; ++r) {
            const int irow = (g << 2) + r;
            float sc[4];
#pragma unroll
            for (int nf = 0; nf < 4; ++nf) {
                const int ddl = (nf << 4) + c - irow + 15;
                sc[nf] = (accs[nf][r] + bf2f(Pdd[wid][irow][ddl])) * 0.125f;
            }
            float mt = fmaxf(fmaxf(sc[0], sc[1]), fmaxf(sc[2], sc[3]));
#pragma unroll
            for (int off = 8; off; off >>= 1) mt = fmaxf(mt, __shfl_xor(mt, off, 16));
            const float mn = fmaxf(m_r[r], mt);
            const float alpha = __expf(m_r[r] - mn);
            m_r[r] = mn;
            float rs = 0.f;
#pragma unroll
            for (int nf = 0; nf < 4; ++nf) {
                const float p = __expf(sc[nf] - mn);
                Pt[wid][irow][(nf << 4) + c] = p;
                rs += p;
            }
#pragma unroll
            for (int off = 8; off; off >>= 1) rs += __shfl_xor(rs, off, 16);
            l_r[r] = l_r[r] * alpha + rs;
#pragma unroll
            for (int nf = 0; nf < 4; ++nf) Oacc[nf][r] *= alpha;
        }

        __builtin_amdgcn_s_setprio(1);
#pragma unroll
        for (int ks = 0; ks < 2; ++ks) {
            f4 pv0 = *(const f4*)&Pt[wid][c][(ks << 5) + (g << 3)];
            f4 pv1 = *(const f4*)&Pt[wid][c][(ks << 5) + (g << 3) + 4];
            float pv[8] = {pv0.x, pv0.y, pv0.z, pv0.w, pv1.x, pv1.y, pv1.z, pv1.w};
            bf16x8 ph, pl;
#pragma unroll
            for (int e = 0; e < 8; ++e) {
                const unsigned short hb = f2bf(pv[e]);
                ph[e] = (short)hb;
                pl[e] = (short)f2bf(pv[e] - bf2f(hb));
            }
#pragma unroll
            for (int nf = 0; nf < 4; ++nf) {
                bf16x8 v_h = *(const bf16x8*)&Vh[(nf << 4) + c][(ks << 5) + (g << 3)];
                bf16x8 v_l = *(const bf16x8*)&Vl[(nf << 4) + c][(ks << 5) + (g << 3)];
                Oacc[nf] = mfma16(ph, v_h, Oacc[nf]);
                Oacc[nf] = mfma16(ph, v_l, Oacc[nf]);
                Oacc[nf] = mfma16(pl, v_h, Oacc[nf]);
            }
        }
        __builtin_amdgcn_s_setprio(0);
    }

    float inv[4];
#pragma unroll
    for (int r = 0; r < 4; ++r) inv[r] = 1.f / l_r[r];
#pragma unroll
    for (int nf = 0; nf < 4; ++nf)
#pragma unroll
        for (int r = 0; r < 4; ++r) {
            const float val = Oacc[nf][r] * inv[r];
            const int sr_ = (g << 2) + r;
            const int s = R0 + sr_;
            const int d = (h << 6) + (nf << 4) + c;
            const int dsw = d ^ (((sr_ >> 1) & 3) << 3);
            const size_t o = ((size_t)(b * SEQ) + s) * DM + dsw;
            const unsigned short hb = f2bf(val);
            cth[o] = hb;
            ctl[o] = f2bf(val - bf2f(hb));
        }
}

extern "C" void kernel_launch(void* const* d_in, const int* in_sizes, int n_in,
                              void* d_out, int out_size, void* d_ws, size_t ws_size,
                              hipStream_t stream)
{
    const float* x  = (const float*)d_in[0];
    const float* wq = (const float*)d_in[1];
    const float* bq = (const float*)d_in[2];
    const float* wk = (const float*)d_in[3];
    const float* bk = (const float*)d_in[4];
    const float* wv = (const float*)d_in[5];
    const float* bv = (const float*)d_in[6];
    const float* wo = (const float*)d_in[7];
    const float* bo = (const float*)d_in[8];
    const float* wr = (const float*)d_in[9];
    const float* u  = (const float*)d_in[10];
    const float* vb = (const float*)d_in[11];
    const float* pe = (const float*)d_in[12];
    float* out = (float*)d_out;
    unsigned short* us = (unsigned short*)d_ws;

    unsigned short* xh  = us;                    // 2097152
    unsigned short* xl  = us + 2097152;
    unsigned short* wb  = us + 4194304;          // 5 x (hi 262144 + lo 262144)
    unsigned short* peh = us + 6815744;          // 524288
    unsigned short* pel = us + 7340032;
    unsigned short* qh  = us + 7864320;          // 2097152 each
    unsigned short* ql  = us + 9961472;
    unsigned short* kh  = us + 12058624;
    unsigned short* kl  = us + 14155776;
    unsigned short* vth = us + 16252928;
    unsigned short* vtl = us + 18350080;
    unsigned short* rmh = us + 20447232;         // 524288 each
    unsigned short* rml = us + 20971520;
    unsigned short* cth = us + 21495808;
    unsigned short* ctl = us + 23592960;
    float* rc = (float*)(us + 25690112);         // 8192 f32

    unsigned short* woh = wb + 3 * 524288;
    unsigned short* wol = woh + 262144;

    dim3 blk(256);
    cvt_all_kernel<<<1920, blk, 0, stream>>>(x, wq, wk, wv, wo, wr,
                                             pe + (size_t)PE_OFF * DM,
                                             xh, xl, wb, peh, pel);
    qkv_rm_kernel<<<832, blk, 0, stream>>>(xh, xl, wb, peh, pel,
                                           bq, bk, bv, u, vb,
                                           qh, ql, kh, kl, vth, vtl,
                                           rmh, rml, rc);
    attn_kernel<<<dim3(8, 8, 8), blk, 0, stream>>>(qh, ql, kh, kl, vth, vtl,
                                                   rmh, rml, rc, cth, ctl);
    out_kernel<<<dim3(8, 32), blk, 0, stream>>>(cth, ctl, woh, wol, bo, out);
}

// Round 19
// 114.817 us; speedup vs baseline: 1.5775x; 1.0005x over previous
//
#include <hip/hip_runtime.h>
#include <math.h>

#define DM 512
#define NH 8
#define DH 64
#define SEQ 512
#define BATCH 8
#define MR 1023
#define PE_OFF 4489

typedef float4 f4;
typedef __attribute__((ext_vector_type(8))) short bf16x8;
typedef __attribute__((ext_vector_type(4))) float f32x4;
typedef __attribute__((ext_vector_type(8))) unsigned short u16x8;
typedef __attribute__((ext_vector_type(4))) unsigned short u16x4;

__device__ __forceinline__ unsigned short f2bf(float f) {
    unsigned x = __float_as_uint(f);
    unsigned r = x + 0x7fffu + ((x >> 16) & 1u);
    return (unsigned short)(r >> 16);
}
__device__ __forceinline__ float bf2f(unsigned short h) {
    return __uint_as_float(((unsigned)h) << 16);
}
__device__ __forceinline__ f32x4 mfma16(bf16x8 a, bf16x8 b, f32x4 c) {
    return __builtin_amdgcn_mfma_f32_16x16x32_bf16(a, b, c, 0, 0, 0);
}
// async global->LDS, 16B per lane, dest = uniform base + lane*16
__device__ __forceinline__ void gll16(const unsigned short* g, unsigned short* l) {
    __builtin_amdgcn_global_load_lds(
        (const __attribute__((address_space(1))) unsigned int*)g,
        (__attribute__((address_space(3))) unsigned int*)l, 16, 0, 0);
}

// ---------------------------------------------------------------------------
// fp32 -> (bf16 hi, bf16 lo), stored PRE-SWIZZLED for gll staging:
// col' = col ^ (((row>>1)&3)<<3)
// ---------------------------------------------------------------------------
__device__ __forceinline__ void cvt8s(const float* __restrict__ src,
                                      unsigned short* __restrict__ hi,
                                      unsigned short* __restrict__ lo, int i) {
    const int row = i >> 9, col = i & 511;
    const int j = (i & ~511) | (col ^ (((row >> 1) & 3) << 3));
    f4 a = *(const f4*)&src[i];
    f4 b = *(const f4*)&src[i + 4];
    float v[8] = {a.x, a.y, a.z, a.w, b.x, b.y, b.z, b.w};
    u16x8 h, l;
#pragma unroll
    for (int e = 0; e < 8; ++e) {
        unsigned short hb = f2bf(v[e]);
        h[e] = hb;
        l[e] = f2bf(v[e] - bf2f(hb));
    }
    *(u16x8*)&hi[j] = h;
    *(u16x8*)&lo[j] = l;
}

__global__ __launch_bounds__(256) void cvt_all_kernel(
    const float* __restrict__ x,
    const float* __restrict__ w0, const float* __restrict__ w1,
    const float* __restrict__ w2, const float* __restrict__ w3,
    const float* __restrict__ w4, const float* __restrict__ pe,
    unsigned short* __restrict__ xh, unsigned short* __restrict__ xl,
    unsigned short* __restrict__ wb,
    unsigned short* __restrict__ peh, unsigned short* __restrict__ pel)
{
    const int bid = blockIdx.x, tid = threadIdx.x;
    if (bid < 1024) {
        cvt8s(x, xh, xl, (bid * 256 + tid) * 8);
    } else if (bid < 1664) {
        const int wsel = (bid - 1024) >> 7;
        const float* src = (wsel == 0) ? w0 : (wsel == 1) ? w1 :
                           (wsel == 2) ? w2 : (wsel == 3) ? w3 : w4;
        unsigned short* hi = wb + (size_t)wsel * 524288;
        cvt8s(src, hi, hi + 262144, (((bid - 1024) & 127) * 256 + tid) * 8);
    } else {
        const int i = ((bid - 1664) * 256 + tid) * 8;
        if (i < 523776) cvt8s(pe, peh, pel, i);
    }
}

// ---------------------------------------------------------------------------
// Split-bf16 GEMM core, 128x64 tile, double-buffered gll staging.
// FULL=1: 3-term (ahbh+ahbl+albh). FULL=0: 2-term (ahbh+ahbl), A-lo unused —
// for error-tolerant outputs (q,k: softmax smooths ~1e-3 relative A error).
// ---------------------------------------------------------------------------
template<int FULL>
__device__ __forceinline__ void gemm_core128(
    const unsigned short* __restrict__ Ah, const unsigned short* __restrict__ Al,
    const unsigned short* __restrict__ Wh, const unsigned short* __restrict__ Wl,
    int m0, int n0, f32x4 acc[4][2],
    unsigned short* LAh, unsigned short* LAl,
    unsigned short* LBh, unsigned short* LBl)
{
    const int tid = threadIdx.x;
    const int lane = tid & 63, wid = tid >> 6;
    const int wm = (wid >> 1) << 6, wn = (wid & 1) << 5;
    const int fr = lane & 15, g = lane >> 4;
    const int crow = lane >> 2;
    const int ccol = (lane & 3) << 3;

#pragma unroll
    for (int i = 0; i < 4; ++i)
#pragma unroll
        for (int j = 0; j < 2; ++j)
            acc[i][j] = (f32x4){0.f, 0.f, 0.f, 0.f};

    const size_t ga1 = (size_t)(m0 + (wid << 4) + crow) * DM + ccol;
    const size_t ga2 = ga1 + (size_t)64 * DM;
    const size_t gb  = (size_t)(n0 + (wid << 4) + crow) * DM + ccol;
    const int lbase = wid << 9;
    const int cswz = (g ^ ((fr >> 1) & 3)) << 3;

    // prologue: stage K-tile 0 into buffer 0
    gll16(Ah + ga1, LAh + lbase);
    gll16(Ah + ga2, LAh + lbase + 2048);
    if (FULL) {
        gll16(Al + ga1, LAl + lbase);
        gll16(Al + ga2, LAl + lbase + 2048);
    }
    gll16(Wh + gb, LBh + lbase);
    gll16(Wl + gb, LBl + lbase);
    __syncthreads();

    int cur = 0;
#pragma unroll
    for (int t = 0; t < 16; ++t) {
        if (t < 15) {                       // issue next tile into other buffer
            const int kn = (t + 1) << 5;
            const int ab = (cur ^ 1) << 12, bb = (cur ^ 1) << 11;
            gll16(Ah + ga1 + kn, LAh + ab + lbase);
            gll16(Ah + ga2 + kn, LAh + ab + lbase + 2048);
            if (FULL) {
                gll16(Al + ga1 + kn, LAl + ab + lbase);
                gll16(Al + ga2 + kn, LAl + ab + lbase + 2048);
            }
            gll16(Wh + gb + kn, LBh + bb + lbase);
            gll16(Wl + gb + kn, LBl + bb + lbase);
        }
        const int ab = cur << 12, bb = cur << 11;
        bf16x8 a_h[4], a_l[4], b_h[2], b_l[2];
#pragma unroll
        for (int mi = 0; mi < 4; ++mi) {
            const int ro = (wm + (mi << 4) + fr) << 5;
            a_h[mi] = *(const bf16x8*)&LAh[ab + ro + cswz];
            if (FULL) a_l[mi] = *(const bf16x8*)&LAl[ab + ro + cswz];
        }
#pragma unroll
        for (int ni = 0; ni < 2; ++ni) {
            const int ro = (wn + (ni << 4) + fr) << 5;
            b_h[ni] = *(const bf16x8*)&LBh[bb + ro + cswz];
            b_l[ni] = *(const bf16x8*)&LBl[bb + ro + cswz];
        }
#pragma unroll
        for (int mi = 0; mi < 4; ++mi)
#pragma unroll
            for (int ni = 0; ni < 2; ++ni) {
                acc[mi][ni] = mfma16(a_h[mi], b_h[ni], acc[mi][ni]);
                acc[mi][ni] = mfma16(a_h[mi], b_l[ni], acc[mi][ni]);
                if (FULL) acc[mi][ni] = mfma16(a_l[mi], b_h[ni], acc[mi][ni]);
            }
        __syncthreads();
        cur ^= 1;
    }
}

#define GEMM_LDS \
    __shared__ unsigned short LAh[2 * 128 * 32], LAl[2 * 128 * 32]; \
    __shared__ unsigned short LBh[2 * 64 * 32], LBl[2 * 64 * 32];

// ---------------------------------------------------------------------------
// Fused QKV projection + Rm/rcorr. Flat grid 832 (rm blocks first).
// q,k: 2-term GEMM; v, rm: 3-term.
// ---------------------------------------------------------------------------
__global__ __launch_bounds__(256) void qkv_rm_kernel(
    const unsigned short* __restrict__ xh, const unsigned short* __restrict__ xl,
    const unsigned short* __restrict__ wb,
    const unsigned short* __restrict__ peh, const unsigned short* __restrict__ pel,
    const float* __restrict__ bq, const float* __restrict__ bk,
    const float* __restrict__ bv, const float* __restrict__ u,
    const float* __restrict__ vb,
    unsigned short* __restrict__ qh, unsigned short* __restrict__ ql,
    unsigned short* __restrict__ kh, unsigned short* __restrict__ kl,
    unsigned short* __restrict__ vth, unsigned short* __restrict__ vtl,
    unsigned short* __restrict__ rmh, unsigned short* __restrict__ rml,
    float* __restrict__ rc)
{
    GEMM_LDS
    const int bid = blockIdx.x;
    const int tid = threadIdx.x, lane = tid & 63, wid = tid >> 6;
    const int wm = (wid >> 1) << 6, wn = (wid & 1) << 5;
    const int fr = lane & 15, g = lane >> 4;

    if (bid < 64) {
        const int n0 = (bid & 7) << 6, m0 = (bid >> 3) << 7;
        const unsigned short* wrh = wb + 4 * 524288;
        const unsigned short* wrl = wrh + 262144;
        f32x4 acc[4][2];
        gemm_core128<1>(peh, pel, wrh, wrl, m0, n0, acc, LAh, LAl, LBh, LBl);

        const int h = n0 >> 6;
        float part[4][4];
        float wgt[2];
#pragma unroll
        for (int ni = 0; ni < 2; ++ni) {
            const int d = wn + (ni << 4) + fr;
            wgt[ni] = vb[(h << 6) + d] - u[(h << 6) + d];
        }
#pragma unroll
        for (int mi = 0; mi < 4; ++mi)
#pragma unroll
            for (int r = 0; r < 4; ++r) part[mi][r] = 0.f;

#pragma unroll
        for (int ni = 0; ni < 2; ++ni) {
            const int n_g = n0 + wn + (ni << 4) + fr;
            const int d = n_g & 63;
#pragma unroll
            for (int mi = 0; mi < 4; ++mi)
#pragma unroll
                for (int r = 0; r < 4; ++r) {
                    const int dd = m0 + wm + (mi << 4) + (g << 2) + r;
                    const float val = acc[mi][ni][r];
                    const size_t o = (((size_t)h << 10) + dd) * DH + d;
                    const unsigned short hb = f2bf(val);
                    rmh[o] = hb;
                    rml[o] = f2bf(val - bf2f(hb));
                    part[mi][r] = fmaf(wgt[ni], val, part[mi][r]);
                }
        }

        __syncthreads();
        float* cbuf = (float*)LAh;
#pragma unroll
        for (int mi = 0; mi < 4; ++mi)
#pragma unroll
            for (int r = 0; r < 4; ++r) {
                float v = part[mi][r];
#pragma unroll
                for (int off = 8; off; off >>= 1) v += __shfl_xor(v, off, 16);
                if (fr == 0)
                    cbuf[((wid & 1) << 7) + wm + (mi << 4) + (g << 2) + r] = v;
            }
        __syncthreads();
        if (tid < 128)
            rc[((size_t)h << 10) + m0 + tid] = cbuf[tid] + cbuf[128 + tid];
        return;
    }

    const int t = bid - 64;
    const int wsel = t >> 8;
    const int rest = t & 255;
    const int n0 = (rest & 7) << 6, m0 = (rest >> 3) << 7;
    const unsigned short* Wh = wb + (size_t)wsel * 524288;
    const unsigned short* Wl = Wh + 262144;
    f32x4 acc[4][2];
    if (wsel < 2)
        gemm_core128<0>(xh, xl, Wh, Wl, m0, n0, acc, LAh, LAl, LBh, LBl);
    else
        gemm_core128<1>(xh, xl, Wh, Wl, m0, n0, acc, LAh, LAl, LBh, LBl);

    const float* bias = (wsel == 0) ? bq : (wsel == 1) ? bk : bv;

    if (wsel < 2) {
        unsigned short* oh = (wsel == 0) ? qh : kh;
        unsigned short* ol = (wsel == 0) ? ql : kl;
#pragma unroll
        for (int ni = 0; ni < 2; ++ni) {
            const int n_g = n0 + wn + (ni << 4) + fr;
            float bvv = bias[n_g] + ((wsel == 0) ? u[n_g] : 0.f);
            const int h = n_g >> 6, d = n_g & 63;
#pragma unroll
            for (int mi = 0; mi < 4; ++mi)
#pragma unroll
                for (int r = 0; r < 4; ++r) {
                    const int m_g = m0 + wm + (mi << 4) + (g << 2) + r;
                    const int b = m_g >> 9, s = m_g & 511;
                    const float val = acc[mi][ni][r] + bvv;
                    const size_t o = ((size_t)(b * NH + h) * SEQ + s) * DH + d;
                    const unsigned short hb = f2bf(val);
                    oh[o] = hb;
                    ol[o] = f2bf(val - bf2f(hb));
                }
        }
    } else {
#pragma unroll
        for (int ni = 0; ni < 2; ++ni) {
            const int n_g = n0 + wn + (ni << 4) + fr;
            const float bvv = bias[n_g];
            const int h = n_g >> 6, d = n_g & 63;
#pragma unroll
            for (int mi = 0; mi < 4; ++mi) {
                const int m_b = m0 + wm + (mi << 4) + (g << 2);
                const int b = m_b >> 9, s = m_b & 511;
                u16x4 hv, lv;
#pragma unroll
                for (int r = 0; r < 4; ++r) {
                    const float val = acc[mi][ni][r] + bvv;
                    hv[r] = f2bf(val);
                    lv[r] = f2bf(val - bf2f(hv[r]));
                }
                const size_t o = ((size_t)(b * NH + h) * DH + d) * SEQ + s;
                *(u16x4*)&vth[o] = hv;
                *(u16x4*)&vtl[o] = lv;
            }
        }
    }
}

// out = ctx @ wo^T + bo  (f32 out). grid (8, 32). 3-term.
__global__ __launch_bounds__(256) void out_kernel(
    const unsigned short* __restrict__ cth, const unsigned short* __restrict__ ctl,
    const unsigned short* __restrict__ woh, const unsigned short* __restrict__ wol,
    const float* __restrict__ bo, float* __restrict__ out)
{
    GEMM_LDS
    const int n0 = blockIdx.x << 6, m0 = blockIdx.y << 7;
    f32x4 acc[4][2];
    gemm_core128<1>(cth, ctl, woh, wol, m0, n0, acc, LAh, LAl, LBh, LBl);

    const int tid = threadIdx.x, lane = tid & 63, wid = tid >> 6;
    const int wm = (wid >> 1) << 6, wn = (wid & 1) << 5;
    const int fr = lane & 15, g = lane >> 4;
#pragma unroll
    for (int ni = 0; ni < 2; ++ni) {
        const int n_g = n0 + wn + (ni << 4) + fr;
        const float bvv = bo[n_g];
#pragma unroll
        for (int mi = 0; mi < 4; ++mi)
#pragma unroll
            for (int r = 0; r < 4; ++r) {
                const int m_g = m0 + wm + (mi << 4) + (g << 2) + r;
                out[(size_t)m_g * DM + n_g] = acc[mi][ni][r] + bvv;
            }
    }
}

// ---------------------------------------------------------------------------
// MFMA flash attention — R14 structure verbatim (57.0 us measured, stable,
// deterministic): K+V LDS-staged, T14 register prefetch, grid 512, Pt f32,
// 3-MFMA PV, ctx stored pre-swizzled for out_kernel's gll.
// ---------------------------------------------------------------------------
__global__ __launch_bounds__(256) void attn_kernel(
    const unsigned short* __restrict__ qh_g, const unsigned short* __restrict__ ql_g,
    const unsigned short* __restrict__ kh_g, const unsigned short* __restrict__ kl_g,
    const unsigned short* __restrict__ vh_g, const unsigned short* __restrict__ vl_g,
    const unsigned short* __restrict__ rmh, const unsigned short* __restrict__ rml,
    const float* __restrict__ rc,
    unsigned short* __restrict__ cth, unsigned short* __restrict__ ctl)
{
    __shared__ unsigned short Kh[64][72], Kl[64][72], Vh[64][72], Vl[64][72];
    __shared__ unsigned short Pdd[4][16][84];
    __shared__ float Pt[4][16][68];

    const int tid = threadIdx.x;
    const int lane = tid & 63, wid = tid >> 6;
    const int g = lane >> 4, c = lane & 15;
    const int i0 = blockIdx.x << 6;
    const int h = blockIdx.y, b = blockIdx.z;
    const int R0 = i0 + (wid << 4);
    const size_t bh = (size_t)(b * NH + h) * (SEQ * DH);

    const int srow = tid >> 3;
    const int sch = (tid & 7) << 3;

    bf16x8 qhf[2], qlf[2];
#pragma unroll
    for (int ks = 0; ks < 2; ++ks) {
        const size_t qo = bh + (size_t)(R0 + c) * DH + (ks << 5) + (g << 3);
        qhf[ks] = *(const bf16x8*)&qh_g[qo];
        qlf[ks] = *(const bf16x8*)&ql_g[qo];
    }

    f32x4 Oacc[4];
#pragma unroll
    for (int nf = 0; nf < 4; ++nf) Oacc[nf] = (f32x4){0.f, 0.f, 0.f, 0.f};
    float m_r[4] = {-3e38f, -3e38f, -3e38f, -3e38f};
    float l_r[4] = {0.f, 0.f, 0.f, 0.f};

    const float* rch = rc + (h << 10);
    const unsigned short* rmhh = rmh + ((size_t)h << 16);
    const unsigned short* rmlh = rml + ((size_t)h << 16);

    u16x8 p0, p1, p2, p3, p4, p5, p6, p7;
    {
        const size_t kb = bh + (size_t)srow * DH + sch;
        p0 = *(const u16x8*)&kh_g[kb];
        p1 = *(const u16x8*)&kh_g[kb + 32 * DH];
        p2 = *(const u16x8*)&kl_g[kb];
        p3 = *(const u16x8*)&kl_g[kb + 32 * DH];
        const size_t vb_ = bh + (size_t)srow * SEQ + sch;
        p4 = *(const u16x8*)&vh_g[vb_];
        p5 = *(const u16x8*)&vh_g[vb_ + 32 * SEQ];
        p6 = *(const u16x8*)&vl_g[vb_];
        p7 = *(const u16x8*)&vl_g[vb_ + 32 * SEQ];
    }

    for (int jt = 0; jt < 8; ++jt) {
        const int j0 = jt << 6;
        __syncthreads();
        *(u16x8*)&Kh[srow][sch] = p0;
        *(u16x8*)&Kh[srow + 32][sch] = p1;
        *(u16x8*)&Kl[srow][sch] = p2;
        *(u16x8*)&Kl[srow + 32][sch] = p3;
        *(u16x8*)&Vh[srow][sch] = p4;
        *(u16x8*)&Vh[srow + 32][sch] = p5;
        *(u16x8*)&Vl[srow][sch] = p6;
        *(u16x8*)&Vl[srow + 32][sch] = p7;
        __syncthreads();
        if (jt < 7) {
            const int jn = j0 + 64;
            const size_t kb = bh + (size_t)(jn + srow) * DH + sch;
            p0 = *(const u16x8*)&kh_g[kb];
            p1 = *(const u16x8*)&kh_g[kb + 32 * DH];
            p2 = *(const u16x8*)&kl_g[kb];
            p3 = *(const u16x8*)&kl_g[kb + 32 * DH];
            const size_t vb_ = bh + (size_t)srow * SEQ + jn + sch;
            p4 = *(const u16x8*)&vh_g[vb_];
            p5 = *(const u16x8*)&vh_g[vb_ + 32 * SEQ];
            p6 = *(const u16x8*)&vl_g[vb_];
            p7 = *(const u16x8*)&vl_g[vb_ + 32 * SEQ];
        }

        __builtin_amdgcn_s_setprio(1);
        f32x4 accs[4];
#pragma unroll
        for (int nf = 0; nf < 4; ++nf) accs[nf] = (f32x4){0.f, 0.f, 0.f, 0.f};
#pragma unroll
        for (int ks = 0; ks < 2; ++ks)
#pragma unroll
            for (int nf = 0; nf < 4; ++nf) {
                bf16x8 b_h = *(const bf16x8*)&Kh[(nf << 4) + c][(ks << 5) + (g << 3)];
                bf16x8 b_l = *(const bf16x8*)&Kl[(nf << 4) + c][(ks << 5) + (g << 3)];
                accs[nf] = mfma16(qhf[ks], b_h, accs[nf]);
                accs[nf] = mfma16(qhf[ks], b_l, accs[nf]);
                accs[nf] = mfma16(qlf[ks], b_h, accs[nf]);
            }

        const int base_g = j0 - R0 + 496;
#pragma unroll
        for (int f = 0; f < 5; ++f) {
            f32x4 ap = (f32x4){0.f, 0.f, 0.f, 0.f};
#pragma unroll
            for (int ks = 0; ks < 2; ++ks) {
                const size_t ro = (size_t)(base_g + (f << 4) + c) * DH
                                + (ks << 5) + (g << 3);
                bf16x8 b_h = *(const bf16x8*)&rmhh[ro];
                bf16x8 b_l = *(const bf16x8*)&rmlh[ro];
                ap = mfma16(qhf[ks], b_h, ap);
                ap = mfma16(qhf[ks], b_l, ap);
                ap = mfma16(qlf[ks], b_h, ap);
            }
            const float rcv = rch[base_g + (f << 4) + c];
#pragma unroll
            for (int r = 0; r < 4; ++r)
                Pdd[wid][(g << 2) + r][(f << 4) + c] = f2bf(ap[r] + rcv);
        }
        __builtin_amdgcn_s_setprio(0);

#pragma unroll
        for (int r = 0; r < 4; ++r) {
            const int irow = (g << 2) + r;
            float sc[4];
#pragma unroll
            for (int nf = 0; nf < 4; ++nf) {
                const int ddl = (nf << 4) + c - irow + 15;
                sc[nf] = (accs[nf][r] + bf2f(Pdd[wid][irow][ddl])) * 0.125f;
            }
            float mt = fmaxf(fmaxf(sc[0], sc[1]), fmaxf(sc[2], sc[3]));
#pragma unroll
            for (int off = 8; off; off >>= 1) mt = fmaxf(mt, __shfl_xor(mt, off, 16));
            const float mn = fmaxf(m_r[r], mt);
            const float alpha = __expf(m_r[r] - mn);
            m_r[r] = mn;
            float rs = 0.f;
#pragma unroll
            for (int nf = 0; nf < 4; ++nf) {
                const float p = __expf(sc[nf] - mn);
                Pt[wid][irow][(nf << 4) + c] = p;
                rs += p;
            }
#pragma unroll
            for (int off = 8; off; off >>= 1) rs += __shfl_xor(rs, off, 16);
            l_r[r] = l_r[r] * alpha + rs;
#pragma unroll
            for (int nf = 0; nf < 4; ++nf) Oacc[nf][r] *= alpha;
        }

        __builtin_amdgcn_s_setprio(1);
#pragma unroll
        for (int ks = 0; ks < 2; ++ks) {
            f4 pv0 = *(const f4*)&Pt[wid][c][(ks << 5) + (g << 3)];
            f4 pv1 = *(const f4*)&Pt[wid][c][(ks << 5) + (g << 3) + 4];
            float pv[8] = {pv0.x, pv0.y, pv0.z, pv0.w, pv1.x, pv1.y, pv1.z, pv1.w};
            bf16x8 ph, pl;
#pragma unroll
            for (int e = 0; e < 8; ++e) {
                const unsigned short hb = f2bf(pv[e]);
                ph[e] = (short)hb;
                pl[e] = (short)f2bf(pv[e] - bf2f(hb));
            }
#pragma unroll
            for (int nf = 0; nf < 4; ++nf) {
                bf16x8 v_h = *(const bf16x8*)&Vh[(nf << 4) + c][(ks << 5) + (g << 3)];
                bf16x8 v_l = *(const bf16x8*)&Vl[(nf << 4) + c][(ks << 5) + (g << 3)];
                Oacc[nf] = mfma16(ph, v_h, Oacc[nf]);
                Oacc[nf] = mfma16(ph, v_l, Oacc[nf]);
                Oacc[nf] = mfma16(pl, v_h, Oacc[nf]);
            }
        }
        __builtin_amdgcn_s_setprio(0);
    }

    float inv[4];
#pragma unroll
    for (int r = 0; r < 4; ++r) inv[r] = 1.f / l_r[r];
#pragma unroll
    for (int nf = 0; nf < 4; ++nf)
#pragma unroll
        for (int r = 0; r < 4; ++r) {
            const float val = Oacc[nf][r] * inv[r];
            const int sr_ = (g << 2) + r;
            const int s = R0 + sr_;
            const int d = (h << 6) + (nf << 4) + c;
            const int dsw = d ^ (((sr_ >> 1) & 3) << 3);
            const size_t o = ((size_t)(b * SEQ) + s) * DM + dsw;
            const unsigned short hb = f2bf(val);
            cth[o] = hb;
            ctl[o] = f2bf(val - bf2f(hb));
        }
}

extern "C" void kernel_launch(void* const* d_in, const int* in_sizes, int n_in,
                              void* d_out, int out_size, void* d_ws, size_t ws_size,
                              hipStream_t stream)
{
    const float* x  = (const float*)d_in[0];
    const float* wq = (const float*)d_in[1];
    const float* bq = (const float*)d_in[2];
    const float* wk = (const float*)d_in[3];
    const float* bk = (const float*)d_in[4];
    const float* wv = (const float*)d_in[5];
    const float* bv = (const float*)d_in[6];
    const float* wo = (const float*)d_in[7];
    const float* bo = (const float*)d_in[8];
    const float* wr = (const float*)d_in[9];
    const float* u  = (const float*)d_in[10];
    const float* vb = (const float*)d_in[11];
    const float* pe = (const float*)d_in[12];
    float* out = (float*)d_out;
    unsigned short* us = (unsigned short*)d_ws;

    unsigned short* xh  = us;                    // 2097152
    unsigned short* xl  = us + 2097152;
    unsigned short* wb  = us + 4194304;          // 5 x (hi 262144 + lo 262144)
    unsigned short* peh = us + 6815744;          // 524288
    unsigned short* pel = us + 7340032;
    unsigned short* qh  = us + 7864320;          // 2097152 each
    unsigned short* ql  = us + 9961472;
    unsigned short* kh  = us + 12058624;
    unsigned short* kl  = us + 14155776;
    unsigned short* vth = us + 16252928;
    unsigned short* vtl = us + 18350080;
    unsigned short* rmh = us + 20447232;         // 524288 each
    unsigned short* rml = us + 20971520;
    unsigned short* cth = us + 21495808;
    unsigned short* ctl = us + 23592960;
    float* rc = (float*)(us + 25690112);         // 8192 f32

    unsigned short* woh = wb + 3 * 524288;
    unsigned short* wol = woh + 262144;

    dim3 blk(256);
    cvt_all_kernel<<<1920, blk, 0, stream>>>(x, wq, wk, wv, wo, wr,
                                             pe + (size_t)PE_OFF * DM,
                                             xh, xl, wb, peh, pel);
    qkv_rm_kernel<<<832, blk, 0, stream>>>(xh, xl, wb, peh, pel,
                                           bq, bk, bv, u, vb,
                                           qh, ql, kh, kl, vth, vtl,
                                           rmh, rml, rc);
    attn_kernel<<<dim3(8, 8, 8), blk, 0, stream>>>(qh, ql, kh, kl, vth, vtl,
                                                   rmh, rml, rc, cth, ctl);
    out_kernel<<<dim3(8, 32), blk, 0, stream>>>(cth, ctl, woh, wol, bo, out);
}